// Round 16
// baseline (10551.816 us; speedup 1.0000x reference)
//
#include <hip/hip_runtime.h>
#include <hip/hip_bf16.h>
#include <cstdint>
#include <cstddef>

namespace {

constexpr int B = 64, S = 128, T = 64, V = 32000, E = 512, H = 512;
constexpr int G4 = 2048;
constexpr int TM1 = T - 1;
constexpr int CHUNK = 32;
constexpr int BH = B * H;           // 32768
constexpr int NT = 128;             // generator N-tile
constexpr int NTILES = V / NT;      // 250
constexpr float MARGIN = 0.02f;
constexpr unsigned NBLK = 256;      // persistent grid (1 block/CU, co-resident)

typedef __attribute__((ext_vector_type(8))) short short8v;
typedef __attribute__((ext_vector_type(4))) float f32x4;

struct GemmSh { float As[16][68]; float Bs[16][132]; };
struct StepSh { float gs[64][17]; };
struct GenSh  { float lds[64][NT + 4]; float pv1[64][4], pv2[64][4], psum[64][4], mrow[64];
                int pi1[64][4], pi2[64][4]; };
struct RedSh  { float sM[256], sS[256], red[256]; float cV[16], rV[16]; int cI[16]; int cN, nxt; };

__device__ __forceinline__ float sigf(float x) { return 1.0f / (1.0f + expf(-x)); }

__device__ __forceinline__ void split3(float w, __hip_bfloat16& a, __hip_bfloat16& b,
                                       __hip_bfloat16& c2) {
    a = __float2bfloat16(w);
    float r = w - __bfloat162float(a);
    b = __float2bfloat16(r);
    c2 = __float2bfloat16(r - __bfloat162float(b));
}

// ================= LLC-coherent (sc0 sc1) access primitives =================
__device__ __forceinline__ unsigned ld_coh_u32(const unsigned* p) {
    unsigned v;
    asm volatile("global_load_dword %0, %1, off sc0 sc1\n\ts_waitcnt vmcnt(0)"
                 : "=v"(v) : "v"(p) : "memory");
    return v;
}
__device__ __forceinline__ void st_coh_u32(unsigned* p, unsigned v) {
    asm volatile("global_store_dword %0, %1, off sc0 sc1" :: "v"(p), "v"(v) : "memory");
}
__device__ __forceinline__ float ld_coh_f32(const float* p) {
    float v;
    asm volatile("global_load_dword %0, %1, off sc0 sc1\n\ts_waitcnt vmcnt(0)"
                 : "=v"(v) : "v"(p));
    return v;
}
__device__ __forceinline__ void st_coh_f32(float* p, float v) {
    asm volatile("global_store_dword %0, %1, off sc0 sc1" :: "v"(p), "v"(v));
}
__device__ __forceinline__ f32x4 ld_coh_f32x4(const float* p) {
    f32x4 v;
    asm volatile("global_load_dwordx4 %0, %1, off sc0 sc1\n\ts_waitcnt vmcnt(0)"
                 : "=v"(v) : "v"(p));
    return v;
}
__device__ __forceinline__ void st_coh_b16(__hip_bfloat16* p, __hip_bfloat16 v) {
    unsigned short us; __builtin_memcpy(&us, &v, 2);
    unsigned u = us;
    asm volatile("global_store_short %0, %1, off sc0 sc1" :: "v"(p), "v"(u));
}
__device__ __forceinline__ void st_coh_b128(__hip_bfloat16* p, short8v v) {
    asm volatile("global_store_dwordx4 %0, %1, off sc0 sc1" :: "v"(p), "v"(v));
}
__device__ __forceinline__ void fence_vm() {
    asm volatile("s_waitcnt vmcnt(0)" ::: "memory");
}

// ---- busy pause: short dependent VALU chain between polls ----
__device__ __forceinline__ void pause_busy() {
    float x = 1.0f;
#pragma unroll
    for (int i = 0; i < 48; ++i)
        asm volatile("v_fmac_f32 %0, %1, %1" : "+v"(x) : "v"(1.0000001f));
    asm volatile("" :: "v"(x));
}

// ---- step A-path: 2-deep pipelined coherent load groups -------------------
__device__ __forceinline__ void issue12_nw(const __hip_bfloat16* p0, const __hip_bfloat16* p1,
                                           const __hip_bfloat16* p2, short8v* q)
{
    asm volatile(
        "global_load_dwordx4 %0, %12, off sc0 sc1\n\t"
        "global_load_dwordx4 %1, %12, off offset:64 sc0 sc1\n\t"
        "global_load_dwordx4 %2, %12, off offset:128 sc0 sc1\n\t"
        "global_load_dwordx4 %3, %12, off offset:192 sc0 sc1\n\t"
        "global_load_dwordx4 %4, %13, off sc0 sc1\n\t"
        "global_load_dwordx4 %5, %13, off offset:64 sc0 sc1\n\t"
        "global_load_dwordx4 %6, %13, off offset:128 sc0 sc1\n\t"
        "global_load_dwordx4 %7, %13, off offset:192 sc0 sc1\n\t"
        "global_load_dwordx4 %8, %14, off sc0 sc1\n\t"
        "global_load_dwordx4 %9, %14, off offset:64 sc0 sc1\n\t"
        "global_load_dwordx4 %10, %14, off offset:128 sc0 sc1\n\t"
        "global_load_dwordx4 %11, %14, off offset:192 sc0 sc1"
        : "=&v"(q[0]), "=&v"(q[1]), "=&v"(q[2]), "=&v"(q[3]),
          "=&v"(q[4]), "=&v"(q[5]), "=&v"(q[6]), "=&v"(q[7]),
          "=&v"(q[8]), "=&v"(q[9]), "=&v"(q[10]), "=&v"(q[11])
        : "v"(p0), "v"(p1), "v"(p2));
}
__device__ __forceinline__ void issue12_w12(const __hip_bfloat16* p0, const __hip_bfloat16* p1,
                                            const __hip_bfloat16* p2, short8v* q)
{
    asm volatile(
        "global_load_dwordx4 %0, %12, off sc0 sc1\n\t"
        "global_load_dwordx4 %1, %12, off offset:64 sc0 sc1\n\t"
        "global_load_dwordx4 %2, %12, off offset:128 sc0 sc1\n\t"
        "global_load_dwordx4 %3, %12, off offset:192 sc0 sc1\n\t"
        "global_load_dwordx4 %4, %13, off sc0 sc1\n\t"
        "global_load_dwordx4 %5, %13, off offset:64 sc0 sc1\n\t"
        "global_load_dwordx4 %6, %13, off offset:128 sc0 sc1\n\t"
        "global_load_dwordx4 %7, %13, off offset:192 sc0 sc1\n\t"
        "global_load_dwordx4 %8, %14, off sc0 sc1\n\t"
        "global_load_dwordx4 %9, %14, off offset:64 sc0 sc1\n\t"
        "global_load_dwordx4 %10, %14, off offset:128 sc0 sc1\n\t"
        "global_load_dwordx4 %11, %14, off offset:192 sc0 sc1\n\t"
        "s_waitcnt vmcnt(12)"
        : "=&v"(q[0]), "=&v"(q[1]), "=&v"(q[2]), "=&v"(q[3]),
          "=&v"(q[4]), "=&v"(q[5]), "=&v"(q[6]), "=&v"(q[7]),
          "=&v"(q[8]), "=&v"(q[9]), "=&v"(q[10]), "=&v"(q[11])
        : "v"(p0), "v"(p1), "v"(p2) : "memory");
}
__device__ __forceinline__ void wait_vm0_fence() {
    asm volatile("s_waitcnt vmcnt(0)" ::: "memory");
    __builtin_amdgcn_sched_barrier(0);
}

// 16 coherent loads (4 pointers x 4 k-subtiles) + waitcnt (gen A side).
__device__ __forceinline__ void ldg16(const __hip_bfloat16* p0, const __hip_bfloat16* p1,
                                      const __hip_bfloat16* p2, const __hip_bfloat16* p3,
                                      short8v* q)
{
    asm volatile(
        "global_load_dwordx4 %0, %16, off sc0 sc1\n\t"
        "global_load_dwordx4 %1, %16, off offset:64 sc0 sc1\n\t"
        "global_load_dwordx4 %2, %16, off offset:128 sc0 sc1\n\t"
        "global_load_dwordx4 %3, %16, off offset:192 sc0 sc1\n\t"
        "global_load_dwordx4 %4, %17, off sc0 sc1\n\t"
        "global_load_dwordx4 %5, %17, off offset:64 sc0 sc1\n\t"
        "global_load_dwordx4 %6, %17, off offset:128 sc0 sc1\n\t"
        "global_load_dwordx4 %7, %17, off offset:192 sc0 sc1\n\t"
        "global_load_dwordx4 %8, %18, off sc0 sc1\n\t"
        "global_load_dwordx4 %9, %18, off offset:64 sc0 sc1\n\t"
        "global_load_dwordx4 %10, %18, off offset:128 sc0 sc1\n\t"
        "global_load_dwordx4 %11, %18, off offset:192 sc0 sc1\n\t"
        "global_load_dwordx4 %12, %19, off sc0 sc1\n\t"
        "global_load_dwordx4 %13, %19, off offset:64 sc0 sc1\n\t"
        "global_load_dwordx4 %14, %19, off offset:128 sc0 sc1\n\t"
        "global_load_dwordx4 %15, %19, off offset:192 sc0 sc1\n\t"
        "s_waitcnt vmcnt(0)"
        : "=&v"(q[0]), "=&v"(q[1]), "=&v"(q[2]), "=&v"(q[3]),
          "=&v"(q[4]), "=&v"(q[5]), "=&v"(q[6]), "=&v"(q[7]),
          "=&v"(q[8]), "=&v"(q[9]), "=&v"(q[10]), "=&v"(q[11]),
          "=&v"(q[12]), "=&v"(q[13]), "=&v"(q[14]), "=&v"(q[15])
        : "v"(p0), "v"(p1), "v"(p2), "v"(p3));
}

// 8 NT-cached loads (2 pointers x 4) + waitcnt (gen Wbf side, fresh region).
__device__ __forceinline__ void ldg8_nt(const __hip_bfloat16* p0, const __hip_bfloat16* p1,
                                        short8v* q)
{
    asm volatile(
        "global_load_dwordx4 %0, %8, off nt\n\t"
        "global_load_dwordx4 %1, %8, off offset:64 nt\n\t"
        "global_load_dwordx4 %2, %8, off offset:128 nt\n\t"
        "global_load_dwordx4 %3, %8, off offset:192 nt\n\t"
        "global_load_dwordx4 %4, %9, off nt\n\t"
        "global_load_dwordx4 %5, %9, off offset:64 nt\n\t"
        "global_load_dwordx4 %6, %9, off offset:128 nt\n\t"
        "global_load_dwordx4 %7, %9, off offset:192 nt\n\t"
        "s_waitcnt vmcnt(0)"
        : "=&v"(q[0]), "=&v"(q[1]), "=&v"(q[2]), "=&v"(q[3]),
          "=&v"(q[4]), "=&v"(q[5]), "=&v"(q[6]), "=&v"(q[7])
        : "v"(p0), "v"(p1));
}

// ---- grid barrier: parallel arrivals + distributed release + busy polling ----
__device__ __forceinline__ void gbar(unsigned* flags, unsigned* rel, unsigned& ep)
{
    unsigned tgt = ++ep;
    fence_vm();
    __syncthreads();
    const int tid = threadIdx.x;
    if (blockIdx.x == 0) {
        if (tid > 0) {
            int spins = 0;
            while (ld_coh_u32(&flags[tid * 32]) < tgt) {
                pause_busy();
                if (++spins > (1 << 18)) break;
            }
        }
        __syncthreads();
        st_coh_u32(&rel[tid * 32], tgt);
    } else {
        if (tid == 0) {
            st_coh_u32(&flags[blockIdx.x * 32], tgt);
            int spins = 0;
            while (ld_coh_u32(&rel[blockIdx.x * 32]) < tgt) {
                pause_busy();
                if (++spins > (1 << 18)) break;
            }
        }
        __syncthreads();
    }
}

// ---------- one-time: split+interleave K=1024 weights [Whh|Wih], rows j'=kh*4+g --
__global__ __launch_bounds__(256)
void split_dec_k(const float* __restrict__ Wih, const float* __restrict__ Whh,
                 const float* __restrict__ bsrc,
                 __hip_bfloat16* __restrict__ P0, __hip_bfloat16* __restrict__ P1,
                 __hip_bfloat16* __restrict__ P2, float* __restrict__ bint)
{
    int row = blockIdx.x;
    int l = row >> 11, jp = row & 2047;
    int kh = jp >> 2, g = jp & 3, src = g * 512 + kh;
    const float* wih = Wih + ((size_t)l * 2048 + src) * 512;
    const float* whh = Whh + ((size_t)l * 2048 + src) * 512;
    size_t ro = (size_t)row * 1024;
    for (int k = threadIdx.x; k < 1024; k += 256) {
        float w = (k < 512) ? whh[k] : wih[k - 512];
        __hip_bfloat16 a, b, c2; split3(w, a, b, c2);
        P0[ro + k] = a; P1[ro + k] = b; P2[ro + k] = c2;
    }
    if (threadIdx.x == 0) bint[row] = bsrc[l * 2048 + src];
}

// ---------- one-time: split+interleave encoder layer-0 Whh, K=512 ----------
__global__ __launch_bounds__(256)
void split_enc_k(const float* __restrict__ Whh,
                 __hip_bfloat16* __restrict__ P0, __hip_bfloat16* __restrict__ P1,
                 __hip_bfloat16* __restrict__ P2)
{
    int row = blockIdx.x;
    int kh = row >> 2, g = row & 3, src = g * 512 + kh;
    const float* whh = Whh + (size_t)src * 512;
    size_t ro = (size_t)row * 512;
    for (int k = threadIdx.x; k < 512; k += 256) {
        __hip_bfloat16 a, b, c2; split3(whh[k], a, b, c2);
        P0[ro + k] = a; P1[ro + k] = b; P2[ro + k] = c2;
    }
}

// ---------- f32 GEMM tile (encoder L0 x-part), gate-interleaved coherent store --
__device__ void gemm_tile(char* shraw, const float* __restrict__ A,
                          const float* __restrict__ Wt, const float* __restrict__ bias,
                          float* __restrict__ C,
                          const int* __restrict__ xseq, int m0, int bx, int by)
{
    GemmSh* sh = reinterpret_cast<GemmSh*>(shraw);
    constexpr int K = 512, BK = 16;
    int tid = threadIdx.x;
    int bm = by * 64, bn = bx * 128;
    int tx = tid & 15, ty = tid >> 4;
    float acc[4][8] = {};

    int lm = tid >> 2, lk = (tid & 3) << 2;
    const float* Arow;
    {
        int mg = m0 + bm + lm; int tt = mg >> 6, b = mg & 63;
        Arow = A + (size_t)xseq[b * S + tt] * K;
    }
    int ln = tid >> 1, lkb = (tid & 1) << 3;
    const float* Brow = Wt + (size_t)(bn + ln) * K;

    for (int k0 = 0; k0 < K; k0 += BK) {
        float4 av = *(const float4*)(Arow + k0 + lk);
        sh->As[lk + 0][lm] = av.x; sh->As[lk + 1][lm] = av.y;
        sh->As[lk + 2][lm] = av.z; sh->As[lk + 3][lm] = av.w;
        float4 bv0 = *(const float4*)(Brow + k0 + lkb);
        float4 bv1 = *(const float4*)(Brow + k0 + lkb + 4);
        sh->Bs[lkb + 0][ln] = bv0.x; sh->Bs[lkb + 1][ln] = bv0.y;
        sh->Bs[lkb + 2][ln] = bv0.z; sh->Bs[lkb + 3][ln] = bv0.w;
        sh->Bs[lkb + 4][ln] = bv1.x; sh->Bs[lkb + 5][ln] = bv1.y;
        sh->Bs[lkb + 6][ln] = bv1.z; sh->Bs[lkb + 7][ln] = bv1.w;
        __syncthreads();
#pragma unroll
        for (int kk = 0; kk < BK; ++kk) {
            const float4 a4  = *(const float4*)&sh->As[kk][ty * 4];
            const float4 b4a = *(const float4*)&sh->Bs[kk][tx * 8];
            const float4 b4b = *(const float4*)&sh->Bs[kk][tx * 8 + 4];
            const float a[4]  = {a4.x, a4.y, a4.z, a4.w};
            const float bb[8] = {b4a.x, b4a.y, b4a.z, b4a.w,
                                 b4b.x, b4b.y, b4b.z, b4b.w};
#pragma unroll
            for (int i = 0; i < 4; ++i)
#pragma unroll
                for (int j = 0; j < 8; ++j)
                    acc[i][j] = fmaf(a[i], bb[j], acc[i][j]);
        }
        __syncthreads();
    }
#pragma unroll
    for (int i = 0; i < 4; ++i) {
        size_t crow = (size_t)(bm + ty * 4 + i) * G4;
#pragma unroll
        for (int j = 0; j < 8; ++j) {
            int cg = bn + tx * 8 + j;
            int jp = ((cg & 511) << 2) | (cg >> 9);   // gate-interleave
            st_coh_f32(C + crow + jp, acc[i][j] + bias[cg]);
        }
    }
}

// ---------- LSTM step via 3-way-split bf16 MFMA, THIN blocks, pipelined ---------
// GATED: x-half (groups 4..7) waits until gate[i*32] >= gneed for i in [0,gate_n).
// done: per-block completion flag published (value dval) after epilogue stores.
template<int KHALF, bool ADDXC, bool MASK, bool GATED>
__device__ void step_body(char* shraw, int blk,
    const __hip_bfloat16* __restrict__ hA0, const __hip_bfloat16* __restrict__ hA1,
    const __hip_bfloat16* __restrict__ hA2,
    const __hip_bfloat16* __restrict__ xA0, const __hip_bfloat16* __restrict__ xA1,
    const __hip_bfloat16* __restrict__ xA2,
    const __hip_bfloat16* __restrict__ W0, const __hip_bfloat16* __restrict__ W1,
    const __hip_bfloat16* __restrict__ W2,
    const float* __restrict__ addsrc, const float* __restrict__ h_in,
    float* __restrict__ h_out, float* __restrict__ c,
    __hip_bfloat16* __restrict__ o0, __hip_bfloat16* __restrict__ o1,
    __hip_bfloat16* __restrict__ o2,
    const int* __restrict__ x_len, int t,
    unsigned* __restrict__ gate, int gate_n, int gneed,
    unsigned* __restrict__ done, unsigned dval)
{
    StepSh* sh = reinterpret_cast<StepSh*>(shraw);
    int tid = threadIdx.x;
    int wave = tid >> 6, lane = tid & 63;
    int lr = lane & 15, kg = (lane >> 4) * 8;
    int arow = wave * 16 + lr;
    int brow = blk * 16 + lr;
    const int KW = 512 * KHALF;
    constexpr int NG = KHALF * 4;

    f32x4 acc0 = {0,0,0,0}, acc1 = {0,0,0,0}, acc2 = {0,0,0,0};
    const size_t aoff = (size_t)arow * 512 + kg;
    const size_t boff = (size_t)brow * KW + kg;

    auto ap = [&](int g, int pl) -> const __hip_bfloat16* {
        const __hip_bfloat16* base;
        if (KHALF == 2 && g >= 4) {
            base = (pl == 0) ? xA0 : (pl == 1) ? xA1 : xA2;
            return base + aoff + (size_t)(g - 4) * 128;
        }
        base = (pl == 0) ? hA0 : (pl == 1) ? hA1 : hA2;
        return base + aoff + (size_t)g * 128;
    };

    short8v q[2][12];
    issue12_nw(ap(0, 0), ap(0, 1), ap(0, 2), q[0]);
#pragma unroll
    for (int g = 0; g < NG; ++g) {
        constexpr bool HASW = (KHALF == 2) && GATED;
        bool boundary = HASW && (g == 3);
        if (g + 1 < NG && !boundary) {
            issue12_w12(ap(g + 1, 0), ap(g + 1, 1), ap(g + 1, 2), q[(g + 1) & 1]);
            __builtin_amdgcn_sched_barrier(0);
        } else {
            wait_vm0_fence();
        }
#pragma unroll
        for (int j = 0; j < 4; ++j) {
            int k0 = g * 128 + j * 32;
            short8v b0 = *(const short8v*)(W0 + boff + k0);
            short8v b1 = *(const short8v*)(W1 + boff + k0);
            short8v b2 = *(const short8v*)(W2 + boff + k0);
            short8v a0 = q[g & 1][j], a1 = q[g & 1][4 + j], a2 = q[g & 1][8 + j];
            acc0 = __builtin_amdgcn_mfma_f32_16x16x32_bf16(a0, b0, acc0, 0, 0, 0);
            acc1 = __builtin_amdgcn_mfma_f32_16x16x32_bf16(a0, b1, acc1, 0, 0, 0);
            acc2 = __builtin_amdgcn_mfma_f32_16x16x32_bf16(a1, b0, acc2, 0, 0, 0);
            acc0 = __builtin_amdgcn_mfma_f32_16x16x32_bf16(a1, b1, acc0, 0, 0, 0);
            acc1 = __builtin_amdgcn_mfma_f32_16x16x32_bf16(a0, b2, acc1, 0, 0, 0);
            acc2 = __builtin_amdgcn_mfma_f32_16x16x32_bf16(a2, b0, acc2, 0, 0, 0);
        }
        if (boundary) {
            // wait for producers of the x-operand (flags >= gneed)
            if (tid < gate_n) {
                int spins = 0;
                while ((int)ld_coh_u32(gate + tid * 32) < gneed) {
                    pause_busy();
                    if (++spins > (1 << 18)) break;
                }
            }
            __syncthreads();
            issue12_nw(ap(4, 0), ap(4, 1), ap(4, 2), q[0]);   // prologue for x-half
        }
    }
    int rb = (lane >> 4) * 4;
#pragma unroll
    for (int r = 0; r < 4; ++r)
        sh->gs[wave * 16 + rb + r][lr] = acc0[r] + acc1[r] + acc2[r];
    __syncthreads();

    int b = tid >> 2, khl = tid & 3;
    int khg = blk * 4 + khl;
    f32x4 add;
    if (ADDXC) add = ld_coh_f32x4(addsrc + (size_t)b * G4 + (size_t)khg * 4);
    else       add = *(const f32x4*)(addsrc + (size_t)khg * 4);
    float gi = sh->gs[b][khl * 4 + 0] + add[0];
    float gf = sh->gs[b][khl * 4 + 1] + add[1];
    float gg = sh->gs[b][khl * 4 + 2] + add[2];
    float go2 = sh->gs[b][khl * 4 + 3] + add[3];
    size_t idx = (size_t)b * H + khg;
    float cold = ld_coh_f32(c + idx);
    float c2 = sigf(gf) * cold + sigf(gi) * tanhf(gg);
    float h2 = sigf(go2) * tanhf(c2);
    if (MASK) {
        bool mk = t < x_len[b];
        if (!mk) { h2 = ld_coh_f32(h_in + idx); c2 = cold; }
    }
    if (h_out) st_coh_f32(h_out + idx, h2);
    st_coh_f32(c + idx, c2);
    __hip_bfloat16 s0, s1, s2; split3(h2, s0, s1, s2);
    st_coh_b16(o0 + idx, s0); st_coh_b16(o1 + idx, s1); st_coh_b16(o2 + idx, s2);
    if (done) {
        fence_vm();
        __syncthreads();
        if (tid == 0) st_coh_u32(done + blk * 32, dval);
    }
}

// ---------- generator tile: A coherent, Wbf via NT-cached loads -----------------
__device__ void gen_body(char* shraw, int bid,
                         const __hip_bfloat16* __restrict__ hbf,
                         const __hip_bfloat16* __restrict__ Wbf,
                         const float* __restrict__ genb,
                         float* __restrict__ part)
{
    GenSh* sh = reinterpret_cast<GenSh*>(shraw);
    int tid = threadIdx.x;
    int wave = tid >> 6, lane = tid & 63;
    int n0 = bid * NT;
    int lr = lane & 15;
    int kg = (lane >> 4) * 8;

    f32x4 acc[4][2];
    const f32x4 zero = {0.f, 0.f, 0.f, 0.f};
#pragma unroll
    for (int i = 0; i < 4; ++i)
#pragma unroll
        for (int j = 0; j < 2; ++j) acc[i][j] = zero;

    const __hip_bfloat16* Arow = hbf + (size_t)lr * 512 + kg;
    const __hip_bfloat16* Brow = Wbf + (size_t)(n0 + wave * 32 + lr) * 512 + kg;
#pragma unroll
    for (int g = 0; g < 4; ++g) {
        short8v qa[16], qb[8];
        ldg16(Arow + g * 128, Arow + 8192 + g * 128,
              Arow + 16384 + g * 128, Arow + 24576 + g * 128, qa);
        ldg8_nt(Brow + g * 128, Brow + 8192 + g * 128, qb);
#pragma unroll
        for (int j = 0; j < 4; ++j) {
#pragma unroll
            for (int mf = 0; mf < 4; ++mf)
#pragma unroll
                for (int nf = 0; nf < 2; ++nf)
                    acc[mf][nf] = __builtin_amdgcn_mfma_f32_16x16x32_bf16(
                        qa[mf * 4 + j], qb[nf * 4 + j], acc[mf][nf], 0, 0, 0);
        }
    }
#pragma unroll
    for (int nf = 0; nf < 2; ++nf) {
        int colLocal = wave * 32 + nf * 16 + lr;
        float bias = genb[n0 + colLocal];
#pragma unroll
        for (int mf = 0; mf < 4; ++mf) {
#pragma unroll
            for (int r = 0; r < 4; ++r) {
                int row = mf * 16 + (lane >> 4) * 4 + r;
                sh->lds[row][colLocal] = acc[mf][nf][r] + bias;
            }
        }
    }
    __syncthreads();

    int row = tid >> 2, q = tid & 3;
    int cbase = q * 32;
    float v1 = -3.4e38f, v2 = -3.4e38f; int i1 = 0x7fffffff, i2 = 0x7fffffff;
    for (int c = 0; c < 32; ++c) {
        float v = sh->lds[row][cbase + c];
        int ci = cbase + c;
        if (v > v1 || (v == v1 && ci < i1)) { v2 = v1; i2 = i1; v1 = v; i1 = ci; }
        else if (v > v2 || (v == v2 && ci < i2)) { v2 = v; i2 = ci; }
    }
    sh->pv1[row][q] = v1; sh->pi1[row][q] = i1; sh->pv2[row][q] = v2; sh->pi2[row][q] = i2;
    __syncthreads();

    float t1 = -3.4e38f, t2 = -3.4e38f; int j1 = 0x7fffffff, j2 = 0x7fffffff;
    if (q == 0) {
        for (int k = 0; k < 4; ++k) {
            float a1 = sh->pv1[row][k]; int a1i = sh->pi1[row][k];
            float a2 = sh->pv2[row][k]; int a2i = sh->pi2[row][k];
            if (a1 > t1 || (a1 == t1 && a1i < j1)) { t2 = t1; j2 = j1; t1 = a1; j1 = a1i; }
            else if (a1 > t2 || (a1 == t2 && a1i < j2)) { t2 = a1; j2 = a1i; }
            if (a2 > t1 || (a2 == t1 && a2i < j1)) { t2 = t1; j2 = j1; t1 = a2; j1 = a2i; }
            else if (a2 > t2 || (a2 == t2 && a2i < j2)) { t2 = a2; j2 = a2i; }
        }
        sh->mrow[row] = t1;
    }
    __syncthreads();
    float m = sh->mrow[row];
    float s = 0.f;
    for (int c = 0; c < 32; ++c) s += expf(sh->lds[row][cbase + c] - m);
    sh->psum[row][q] = s;
    __syncthreads();
    if (q == 0) {
        float sum = sh->psum[row][0] + sh->psum[row][1] + sh->psum[row][2] + sh->psum[row][3];
        float* p = part + ((size_t)bid * B + row) * 6;
        st_coh_f32(p + 0, t1);
        st_coh_f32(p + 1, t2);
        st_coh_u32((unsigned*)(p + 2), (unsigned)(n0 + j1));
        st_coh_u32((unsigned*)(p + 3), (unsigned)(n0 + j2));
        st_coh_f32(p + 4, sum);
    }
}

// ---------- reduce: combine partials, exact-f32 argmax + gold, emit x-splits ----
__device__ void reduce_body(char* shraw, int b,
                            const float* __restrict__ part,
                            const float* __restrict__ h,
                            const float* __restrict__ genW, const float* __restrict__ genb,
                            const float* __restrict__ tgt_emb,
                            const int* __restrict__ y_seqs, const int* __restrict__ teacher,
                            float* __restrict__ outp,
                            __hip_bfloat16* __restrict__ xp0, __hip_bfloat16* __restrict__ xp1,
                            __hip_bfloat16* __restrict__ xp2, int t,
                            unsigned* __restrict__ xrdy)
{
    RedSh* sh = reinterpret_cast<RedSh*>(shraw);
    int tid = threadIdx.x;
    int y = y_seqs[b * T + t + 1];
    const float* hrow = h + (size_t)b * 512;
    float h_a = ld_coh_f32(hrow + tid);
    float h_b = ld_coh_f32(hrow + tid + 256);

    float p_top1 = -3.4e38f, p_top2 = -3.4e38f, p_sum = 0.f;
    int p_i1 = 0x7fffffff, p_i2 = 0x7fffffff;
    if (tid < NTILES) {
        const float* p = part + ((size_t)tid * B + b) * 6;
        f32x4 v4 = ld_coh_f32x4(p);
        p_top1 = v4[0]; p_top2 = v4[1];
        p_i1 = __float_as_int(v4[2]);
        p_i2 = __float_as_int(v4[3]);
        p_sum = ld_coh_f32(p + 4);
    }
    sh->sM[tid] = p_top1; __syncthreads();
    for (int o = 128; o; o >>= 1) { if (tid < o) sh->sM[tid] = fmaxf(sh->sM[tid], sh->sM[tid + o]); __syncthreads(); }
    float M = sh->sM[0];
    if (tid == 0) sh->cN = 0;
    __syncthreads();

    float Ssum = (tid < NTILES) ? p_sum * expf(p_top1 - M) : 0.f;
    if (tid < NTILES) {
        if (p_top1 >= M - MARGIN) { int j = atomicAdd(&sh->cN, 1); if (j < 16) { sh->cV[j] = p_top1; sh->cI[j] = p_i1; } }
        if (p_top2 >= M - MARGIN) { int j = atomicAdd(&sh->cN, 1); if (j < 16) { sh->cV[j] = p_top2; sh->cI[j] = p_i2; } }
    }
    sh->sS[tid] = Ssum; __syncthreads();
    for (int o = 128; o; o >>= 1) { if (tid < o) sh->sS[tid] += sh->sS[tid + o]; __syncthreads(); }
    float lse = M + logf(sh->sS[0]);
    int nc = sh->cN < 16 ? sh->cN : 16;

    {
        const float* wrow = genW + (size_t)y * 512;
        float s = fmaf(h_a, wrow[tid], 0.f) + h_b * wrow[tid + 256];
        sh->red[tid] = s; __syncthreads();
        for (int o = 128; o; o >>= 1) { if (tid < o) sh->red[tid] += sh->red[tid + o]; __syncthreads(); }
        if (tid == 0) outp[b * TM1 + t] = sh->red[0] + genb[y] - lse;
        __syncthreads();
    }
    if (nc > 1) {
        for (int j = 0; j < nc; ++j) {
            const float* wrow = genW + (size_t)sh->cI[j] * 512;
            float s = fmaf(h_a, wrow[tid], 0.f) + h_b * wrow[tid + 256];
            sh->red[tid] = s; __syncthreads();
            for (int o = 128; o; o >>= 1) { if (tid < o) sh->red[tid] += sh->red[tid + o]; __syncthreads(); }
            if (tid == 0) sh->rV[j] = sh->red[0] + genb[sh->cI[j]];
            __syncthreads();
        }
    }
    if (tid == 0) {
        int winner;
        if (nc == 1) winner = sh->cI[0];
        else {
            float bv = -3.4e38f; int bi = 0x7fffffff;
            for (int j = 0; j < nc; ++j)
                if (sh->rV[j] > bv || (sh->rV[j] == bv && sh->cI[j] < bi)) { bv = sh->rV[j]; bi = sh->cI[j]; }
            winner = bi;
        }
        sh->nxt = (teacher[t] > 0) ? y : winner;
    }
    __syncthreads();
    int tok = sh->nxt;
    for (int k = tid; k < 512; k += 256) {
        float w = tgt_emb[(size_t)tok * 512 + k];
        __hip_bfloat16 s0, s1, s2; split3(w, s0, s1, s2);
        st_coh_b16(xp0 + (size_t)b * 512 + k, s0);
        st_coh_b16(xp1 + (size_t)b * 512 + k, s1);
        st_coh_b16(xp2 + (size_t)b * 512 + k, s2);
    }
    fence_vm();
    __syncthreads();
    if (tid == 0 && xrdy) st_coh_u32(xrdy + b * 32, (unsigned)(t + 1));
}

// ---------- the whole network in one persistent kernel --------------------------
struct Args {
    const int *x_seqs, *x_len, *y_seqs, *teacher;
    const float *src_emb, *tgt_emb, *eWih, *eb, *genW, *genb;
    float* Xc;
    const __hip_bfloat16 *eP0, *eP1, *eP2;
    const __hip_bfloat16 *e1P0, *e1P1, *e1P2;
    const float* ebint;
    const __hip_bfloat16 *dP0, *dP1, *dP2;
    const float* bint;
    float *hf32, *cbuf, *dech1;        // dech1: [2][BH] parity-buffered
    __hip_bfloat16 *P, *xP, *Wbf;
    float* part;
    float* outp;
    unsigned *flags, *rel, *xrdy, *l0done, *gdone;
};

__global__ __launch_bounds__(256, 1)
void persist_k(Args a)
{
    __shared__ __align__(16) char shpool[40960];
    unsigned ep = 0;
    const int bid = blockIdx.x;
    const int tid = threadIdx.x;
    const int gtid = bid * 256 + tid;
    const int GS = NBLK * 256;

    auto Pl = [&](int l, int slot, int pl) {
        return a.P + (((size_t)(l * 2 + slot)) * 3 + pl) * BH; };

    // ---- init: zero slot-0 state + c (coherent) ----
    for (int i = gtid; i < BH; i += GS) {
        st_coh_f32(a.hf32 + i, 0.f); st_coh_f32(a.hf32 + 2 * BH + i, 0.f);
        st_coh_f32(a.cbuf + i, 0.f); st_coh_f32(a.cbuf + BH + i, 0.f);
    }
    {
        unsigned* p0 = (unsigned*)Pl(0, 0, 0);
        unsigned* p1 = (unsigned*)Pl(1, 0, 0);
        for (int i = gtid; i < 3 * BH / 2; i += GS) { st_coh_u32(p0 + i, 0u); st_coh_u32(p1 + i, 0u); }
    }
    gbar(a.flags, a.rel, ep);

    // ---- encoder: L0/L1 pipelined (phase t: L0 step t | L1 step t-1) ----
    for (int c0 = 0; c0 < S; c0 += CHUNK) {
        for (int tile = bid; tile < 512; tile += NBLK)
            gemm_tile(shpool, a.src_emb, a.eWih, a.eb, a.Xc,
                      a.x_seqs, c0 * B, tile & 15, tile >> 4);
        gbar(a.flags, a.rel, ep);
        for (int tl = 0; tl < CHUNK; ++tl) {
            int t = c0 + tl;
            if (bid < 128) {
                step_body<1, true, true, false>(shpool, bid,
                    Pl(0, t & 1, 0), Pl(0, t & 1, 1), Pl(0, t & 1, 2),
                    nullptr, nullptr, nullptr,
                    a.eP0, a.eP1, a.eP2,
                    a.Xc + (size_t)tl * B * G4,
                    a.hf32 + (size_t)(t & 1) * BH, a.hf32 + (size_t)((t + 1) & 1) * BH,
                    a.cbuf,
                    Pl(0, (t + 1) & 1, 0), Pl(0, (t + 1) & 1, 1), Pl(0, (t + 1) & 1, 2),
                    a.x_len, t, nullptr, 0, 0, nullptr, 0);
            } else if (t >= 1) {
                int u = t - 1;
                step_body<2, false, true, false>(shpool, bid - 128,
                    Pl(1, u & 1, 0), Pl(1, u & 1, 1), Pl(1, u & 1, 2),
                    Pl(0, t & 1, 0), Pl(0, t & 1, 1), Pl(0, t & 1, 2),
                    a.e1P0, a.e1P1, a.e1P2,
                    a.ebint,
                    a.hf32 + (size_t)(2 + (u & 1)) * BH, a.hf32 + (size_t)(2 + ((u + 1) & 1)) * BH,
                    a.cbuf + BH,
                    Pl(1, (u + 1) & 1, 0), Pl(1, (u + 1) & 1, 1), Pl(1, (u + 1) & 1, 2),
                    a.x_len, u, nullptr, 0, 0, nullptr, 0);
            }
            gbar(a.flags, a.rel, ep);
        }
    }
    if (bid < 128) {           // drain: L1 step 127
        int u = S - 1;
        step_body<2, false, true, false>(shpool, bid,
            Pl(1, u & 1, 0), Pl(1, u & 1, 1), Pl(1, u & 1, 2),
            Pl(0, (u + 1) & 1, 0), Pl(0, (u + 1) & 1, 1), Pl(0, (u + 1) & 1, 2),
            a.e1P0, a.e1P1, a.e1P2,
            a.ebint,
            a.hf32 + (size_t)(2 + (u & 1)) * BH, a.hf32 + (size_t)(2 + ((u + 1) & 1)) * BH,
            a.cbuf + BH,
            Pl(1, (u + 1) & 1, 0), Pl(1, (u + 1) & 1, 1), Pl(1, (u + 1) & 1, 2),
            a.x_len, u, nullptr, 0, 0, nullptr, 0);
    }
    gbar(a.flags, a.rel, ep);

    // ---- genW -> bf16 (fresh region) + BOS x-splits ----
    {
        const int N8 = V * E / 8;
        for (int i = gtid; i < N8; i += GS) {
            float4 x = *(const float4*)(a.genW + (size_t)i * 8);
            float4 y = *(const float4*)(a.genW + (size_t)i * 8 + 4);
            __hip_bfloat16 tmp[8];
            tmp[0] = __float2bfloat16(x.x); tmp[1] = __float2bfloat16(x.y);
            tmp[2] = __float2bfloat16(x.z); tmp[3] = __float2bfloat16(x.w);
            tmp[4] = __float2bfloat16(y.x); tmp[5] = __float2bfloat16(y.y);
            tmp[6] = __float2bfloat16(y.z); tmp[7] = __float2bfloat16(y.w);
            st_coh_b128(a.Wbf + (size_t)i * 8, *(const short8v*)tmp);
        }
        for (int i = gtid; i < BH; i += GS) {
            int k = i & 511;
            float w = a.tgt_emb[512 + k];          // BOS token = 1
            __hip_bfloat16 s0, s1, s2; split3(w, s0, s1, s2);
            st_coh_b16(a.xP + i, s0);
            st_coh_b16(a.xP + BH + i, s1);
            st_coh_b16(a.xP + 2 * BH + i, s2);
        }
    }
    gbar(a.flags, a.rel, ep);

    // ---- decoder: ONE phase per step, flag-chained --------------------------
    // Group A (0..127):  L0(t)[x gated on xrdy>=t] -> l0done=t+1
    //                    L1(t)[x gated on l0done>=t+1], writes dech1[t&1]
    // Group B (128..255): gen(t-1) (2 tiles) -> gdone=t;
    //                    blocks 128..191: poll gdone>=t, reduce(t-1) -> xrdy=t
    for (int t = 0; t <= TM1; ++t) {
        int si = t & 1, so = si ^ 1;
        if (bid < 128 && t < TM1) {
            step_body<2, false, false, true>(shpool, bid,
                Pl(0, si, 0), Pl(0, si, 1), Pl(0, si, 2),
                a.xP, a.xP + BH, a.xP + 2 * BH,
                a.dP0, a.dP1, a.dP2, a.bint,
                nullptr, nullptr, a.cbuf,
                Pl(0, so, 0), Pl(0, so, 1), Pl(0, so, 2),
                nullptr, 0, a.xrdy, 64, t, a.l0done, (unsigned)(t + 1));
            step_body<2, false, false, true>(shpool, bid,
                Pl(1, si, 0), Pl(1, si, 1), Pl(1, si, 2),
                Pl(0, so, 0), Pl(0, so, 1), Pl(0, so, 2),
                a.dP0 + (size_t)G4 * 1024, a.dP1 + (size_t)G4 * 1024,
                a.dP2 + (size_t)G4 * 1024, a.bint + G4,
                nullptr, a.dech1 + (size_t)(t & 1) * BH, a.cbuf + BH,
                Pl(1, so, 0), Pl(1, so, 1), Pl(1, so, 2),
                nullptr, 0, a.l0done, 128, t + 1, nullptr, 0);
        } else if (bid >= 128 && t >= 1) {
            int u = t - 1;
            const __hip_bfloat16* hbf = Pl(1, (u + 1) & 1, 0);
            for (int tile = bid - 128; tile < NTILES; tile += 128)
                gen_body(shpool, tile, hbf, a.Wbf, a.genb, a.part);
            fence_vm();
            __syncthreads();
            if (tid == 0) st_coh_u32(a.gdone + (bid - 128) * 32, (unsigned)t);
            if (bid < 192) {
                if (tid < 128) {
                    int spins = 0;
                    while ((int)ld_coh_u32(a.gdone + tid * 32) < t) {
                        pause_busy();
                        if (++spins > (1 << 18)) break;
                    }
                }
                __syncthreads();
                reduce_body(shpool, bid - 128, a.part,
                            a.dech1 + (size_t)(u & 1) * BH,
                            a.genW, a.genb, a.tgt_emb,
                            a.y_seqs, a.teacher, a.outp,
                            a.xP, a.xP + BH, a.xP + 2 * BH, u,
                            (t < TM1) ? a.xrdy : nullptr);
            }
        }
        gbar(a.flags, a.rel, ep);
    }
}

} // namespace

extern "C" void kernel_launch(void* const* d_in, const int* in_sizes, int n_in,
                              void* d_out, int out_size, void* d_ws, size_t ws_size,
                              hipStream_t stream)
{
    (void)in_sizes; (void)n_in; (void)out_size;
    const int*   x_seqs  = (const int*)  d_in[0];
    const int*   x_len   = (const int*)  d_in[1];
    const int*   y_seqs  = (const int*)  d_in[2];
    const int*   teacher = (const int*)  d_in[3];
    const float* src_emb = (const float*)d_in[4];
    const float* tgt_emb = (const float*)d_in[5];
    const float* eWih    = (const float*)d_in[6];
    const float* eWhh    = (const float*)d_in[7];
    const float* eb      = (const float*)d_in[8];
    const float* dWih    = (const float*)d_in[9];
    const float* dWhh    = (const float*)d_in[10];
    const float* db      = (const float*)d_in[11];
    const float* genW    = (const float*)d_in[12];
    const float* genb    = (const float*)d_in[13];

    float* w = (float*)d_ws;
    size_t off = 0;
    auto take = [&](size_t n) { float* p = w + off; off += n; return p; };
    auto takeb = [&](size_t n) { return (__hip_bfloat16*)take((n + 1) / 2); };

    unsigned* flags  = (unsigned*)take(256 * 32);
    unsigned* rel    = (unsigned*)take(256 * 32);
    unsigned* xrdy   = (unsigned*)take(64 * 32);
    unsigned* l0done = (unsigned*)take(128 * 32);
    unsigned* gdone  = (unsigned*)take(128 * 32);
    float* Xc = take((size_t)CHUNK * B * G4);                     // 16.78 MB
    __hip_bfloat16* eP0  = takeb((size_t)G4 * 512);
    __hip_bfloat16* eP1  = takeb((size_t)G4 * 512);
    __hip_bfloat16* eP2  = takeb((size_t)G4 * 512);
    __hip_bfloat16* e1P0 = takeb((size_t)G4 * 1024);
    __hip_bfloat16* e1P1 = takeb((size_t)G4 * 1024);
    __hip_bfloat16* e1P2 = takeb((size_t)G4 * 1024);
    float* ebint = take((size_t)G4);
    __hip_bfloat16* dP0 = takeb((size_t)2 * G4 * 1024);
    __hip_bfloat16* dP1 = takeb((size_t)2 * G4 * 1024);
    __hip_bfloat16* dP2 = takeb((size_t)2 * G4 * 1024);
    float* bint  = take(2 * (size_t)G4);
    float* hf32  = take(4 * (size_t)BH);
    float* cbuf  = take(2 * (size_t)BH);
    float* dech1 = take(2 * (size_t)BH);          // parity-buffered
    __hip_bfloat16* P  = takeb((size_t)12 * BH);
    __hip_bfloat16* xP = takeb((size_t)3 * BH);
    float* part_f = take((size_t)NTILES * B * 6);
    // FRESH Wbf region (32.8MB): never cached-accessed -> nt reads are safe
    __hip_bfloat16* Wbf = takeb((size_t)V * E);
    if (ws_size < off * sizeof(float)) return;    // fail visibly if ws too small

    dim3 tpb256(256);
    split_enc_k<<<dim3(G4), tpb256, 0, stream>>>(eWhh, eP0, eP1, eP2);
    split_dec_k<<<dim3(G4), tpb256, 0, stream>>>(
        eWih + (size_t)G4 * E, eWhh + (size_t)G4 * E, eb + G4, e1P0, e1P1, e1P2, ebint);
    split_dec_k<<<dim3(2 * G4), tpb256, 0, stream>>>(
        dWih, dWhh, db, dP0, dP1, dP2, bint);
    hipError_t _e = hipMemsetAsync(flags, 0,
        (256 + 256 + 64 + 128 + 128) * 32 * sizeof(unsigned), stream);
    (void)_e;

    Args a;
    a.x_seqs = x_seqs; a.x_len = x_len; a.y_seqs = y_seqs; a.teacher = teacher;
    a.src_emb = src_emb; a.tgt_emb = tgt_emb; a.eWih = eWih; a.eb = eb;
    a.genW = genW; a.genb = genb;
    a.Xc = Xc;
    a.eP0 = eP0; a.eP1 = eP1; a.eP2 = eP2;
    a.e1P0 = e1P0; a.e1P1 = e1P1; a.e1P2 = e1P2; a.ebint = ebint;
    a.dP0 = dP0; a.dP1 = dP1; a.dP2 = dP2; a.bint = bint;
    a.hf32 = hf32; a.cbuf = cbuf; a.dech1 = dech1;
    a.P = P; a.xP = xP;
    a.Wbf = Wbf;
    a.part = part_f;
    a.outp = (float*)d_out;
    a.flags = flags; a.rel = rel; a.xrdy = xrdy; a.l0done = l0done; a.gdone = gdone;

    persist_k<<<dim3(NBLK), tpb256, 0, stream>>>(a);
}

// Round 17
// 9415.914 us; speedup vs baseline: 1.1206x; 1.1206x over previous
//
#include <hip/hip_runtime.h>
#include <hip/hip_bf16.h>
#include <cstdint>
#include <cstddef>

namespace {

constexpr int B = 64, S = 128, T = 64, V = 32000, E = 512, H = 512;
constexpr int G4 = 2048;
constexpr int TM1 = T - 1;
constexpr int CHUNK = 32;
constexpr int BH = B * H;           // 32768
constexpr int NT = 128;             // generator N-tile
constexpr int NTILES = V / NT;      // 250
constexpr float MARGIN = 0.02f;
constexpr unsigned NBLK = 256;      // persistent grid (1 block/CU, co-resident)

typedef __attribute__((ext_vector_type(8))) short short8v;
typedef __attribute__((ext_vector_type(4))) float f32x4;

struct GemmSh { float As[16][68]; float Bs[16][132]; };
struct StepSh { float gs[64][17]; };
struct GenSh  { float lds[64][NT + 4]; float pv1[64][4], pv2[64][4], psum[64][4], mrow[64];
                int pi1[64][4], pi2[64][4]; };
struct RedSh  { float sM[256], sS[256], red[256]; float cV[16], rV[16]; int cI[16]; int cN, nxt; };

__device__ __forceinline__ float sigf(float x) { return 1.0f / (1.0f + expf(-x)); }

__device__ __forceinline__ void split3(float w, __hip_bfloat16& a, __hip_bfloat16& b,
                                       __hip_bfloat16& c2) {
    a = __float2bfloat16(w);
    float r = w - __bfloat162float(a);
    b = __float2bfloat16(r);
    c2 = __float2bfloat16(r - __bfloat162float(b));
}

// ================= LLC-coherent (sc0 sc1) access primitives =================
__device__ __forceinline__ unsigned ld_coh_u32(const unsigned* p) {
    unsigned v;
    asm volatile("global_load_dword %0, %1, off sc0 sc1\n\ts_waitcnt vmcnt(0)"
                 : "=v"(v) : "v"(p) : "memory");
    return v;
}
__device__ __forceinline__ void st_coh_u32(unsigned* p, unsigned v) {
    asm volatile("global_store_dword %0, %1, off sc0 sc1" :: "v"(p), "v"(v) : "memory");
}
__device__ __forceinline__ float ld_coh_f32(const float* p) {
    float v;
    asm volatile("global_load_dword %0, %1, off sc0 sc1\n\ts_waitcnt vmcnt(0)"
                 : "=v"(v) : "v"(p));
    return v;
}
__device__ __forceinline__ void st_coh_f32(float* p, float v) {
    asm volatile("global_store_dword %0, %1, off sc0 sc1" :: "v"(p), "v"(v));
}
__device__ __forceinline__ f32x4 ld_coh_f32x4(const float* p) {
    f32x4 v;
    asm volatile("global_load_dwordx4 %0, %1, off sc0 sc1\n\ts_waitcnt vmcnt(0)"
                 : "=v"(v) : "v"(p));
    return v;
}
__device__ __forceinline__ void st_coh_b16(__hip_bfloat16* p, __hip_bfloat16 v) {
    unsigned short us; __builtin_memcpy(&us, &v, 2);
    unsigned u = us;
    asm volatile("global_store_short %0, %1, off sc0 sc1" :: "v"(p), "v"(u));
}
__device__ __forceinline__ void st_coh_b128(__hip_bfloat16* p, short8v v) {
    asm volatile("global_store_dwordx4 %0, %1, off sc0 sc1" :: "v"(p), "v"(v));
}
__device__ __forceinline__ void fence_vm() {
    asm volatile("s_waitcnt vmcnt(0)" ::: "memory");
}

// ---- busy pause: short dependent VALU chain between polls ----
__device__ __forceinline__ void pause_busy() {
    float x = 1.0f;
#pragma unroll
    for (int i = 0; i < 48; ++i)
        asm volatile("v_fmac_f32 %0, %1, %1" : "+v"(x) : "v"(1.0000001f));
    asm volatile("" :: "v"(x));
}

// ---- step A-path: 2-deep pipelined coherent load groups -------------------
__device__ __forceinline__ void issue12_nw(const __hip_bfloat16* p0, const __hip_bfloat16* p1,
                                           const __hip_bfloat16* p2, short8v* q)
{
    asm volatile(
        "global_load_dwordx4 %0, %12, off sc0 sc1\n\t"
        "global_load_dwordx4 %1, %12, off offset:64 sc0 sc1\n\t"
        "global_load_dwordx4 %2, %12, off offset:128 sc0 sc1\n\t"
        "global_load_dwordx4 %3, %12, off offset:192 sc0 sc1\n\t"
        "global_load_dwordx4 %4, %13, off sc0 sc1\n\t"
        "global_load_dwordx4 %5, %13, off offset:64 sc0 sc1\n\t"
        "global_load_dwordx4 %6, %13, off offset:128 sc0 sc1\n\t"
        "global_load_dwordx4 %7, %13, off offset:192 sc0 sc1\n\t"
        "global_load_dwordx4 %8, %14, off sc0 sc1\n\t"
        "global_load_dwordx4 %9, %14, off offset:64 sc0 sc1\n\t"
        "global_load_dwordx4 %10, %14, off offset:128 sc0 sc1\n\t"
        "global_load_dwordx4 %11, %14, off offset:192 sc0 sc1"
        : "=&v"(q[0]), "=&v"(q[1]), "=&v"(q[2]), "=&v"(q[3]),
          "=&v"(q[4]), "=&v"(q[5]), "=&v"(q[6]), "=&v"(q[7]),
          "=&v"(q[8]), "=&v"(q[9]), "=&v"(q[10]), "=&v"(q[11])
        : "v"(p0), "v"(p1), "v"(p2));
}
__device__ __forceinline__ void issue12_w12(const __hip_bfloat16* p0, const __hip_bfloat16* p1,
                                            const __hip_bfloat16* p2, short8v* q)
{
    asm volatile(
        "global_load_dwordx4 %0, %12, off sc0 sc1\n\t"
        "global_load_dwordx4 %1, %12, off offset:64 sc0 sc1\n\t"
        "global_load_dwordx4 %2, %12, off offset:128 sc0 sc1\n\t"
        "global_load_dwordx4 %3, %12, off offset:192 sc0 sc1\n\t"
        "global_load_dwordx4 %4, %13, off sc0 sc1\n\t"
        "global_load_dwordx4 %5, %13, off offset:64 sc0 sc1\n\t"
        "global_load_dwordx4 %6, %13, off offset:128 sc0 sc1\n\t"
        "global_load_dwordx4 %7, %13, off offset:192 sc0 sc1\n\t"
        "global_load_dwordx4 %8, %14, off sc0 sc1\n\t"
        "global_load_dwordx4 %9, %14, off offset:64 sc0 sc1\n\t"
        "global_load_dwordx4 %10, %14, off offset:128 sc0 sc1\n\t"
        "global_load_dwordx4 %11, %14, off offset:192 sc0 sc1\n\t"
        "s_waitcnt vmcnt(12)"
        : "=&v"(q[0]), "=&v"(q[1]), "=&v"(q[2]), "=&v"(q[3]),
          "=&v"(q[4]), "=&v"(q[5]), "=&v"(q[6]), "=&v"(q[7]),
          "=&v"(q[8]), "=&v"(q[9]), "=&v"(q[10]), "=&v"(q[11])
        : "v"(p0), "v"(p1), "v"(p2) : "memory");
}
__device__ __forceinline__ void wait_vm0_fence() {
    asm volatile("s_waitcnt vmcnt(0)" ::: "memory");
    __builtin_amdgcn_sched_barrier(0);
}

// 16 coherent loads (4 pointers x 4 k-subtiles) + waitcnt (gen A side).
__device__ __forceinline__ void ldg16(const __hip_bfloat16* p0, const __hip_bfloat16* p1,
                                      const __hip_bfloat16* p2, const __hip_bfloat16* p3,
                                      short8v* q)
{
    asm volatile(
        "global_load_dwordx4 %0, %16, off sc0 sc1\n\t"
        "global_load_dwordx4 %1, %16, off offset:64 sc0 sc1\n\t"
        "global_load_dwordx4 %2, %16, off offset:128 sc0 sc1\n\t"
        "global_load_dwordx4 %3, %16, off offset:192 sc0 sc1\n\t"
        "global_load_dwordx4 %4, %17, off sc0 sc1\n\t"
        "global_load_dwordx4 %5, %17, off offset:64 sc0 sc1\n\t"
        "global_load_dwordx4 %6, %17, off offset:128 sc0 sc1\n\t"
        "global_load_dwordx4 %7, %17, off offset:192 sc0 sc1\n\t"
        "global_load_dwordx4 %8, %18, off sc0 sc1\n\t"
        "global_load_dwordx4 %9, %18, off offset:64 sc0 sc1\n\t"
        "global_load_dwordx4 %10, %18, off offset:128 sc0 sc1\n\t"
        "global_load_dwordx4 %11, %18, off offset:192 sc0 sc1\n\t"
        "global_load_dwordx4 %12, %19, off sc0 sc1\n\t"
        "global_load_dwordx4 %13, %19, off offset:64 sc0 sc1\n\t"
        "global_load_dwordx4 %14, %19, off offset:128 sc0 sc1\n\t"
        "global_load_dwordx4 %15, %19, off offset:192 sc0 sc1\n\t"
        "s_waitcnt vmcnt(0)"
        : "=&v"(q[0]), "=&v"(q[1]), "=&v"(q[2]), "=&v"(q[3]),
          "=&v"(q[4]), "=&v"(q[5]), "=&v"(q[6]), "=&v"(q[7]),
          "=&v"(q[8]), "=&v"(q[9]), "=&v"(q[10]), "=&v"(q[11]),
          "=&v"(q[12]), "=&v"(q[13]), "=&v"(q[14]), "=&v"(q[15])
        : "v"(p0), "v"(p1), "v"(p2), "v"(p3));
}

// 8 NT-cached loads (2 pointers x 4) + waitcnt (gen Wbf side, fresh region).
__device__ __forceinline__ void ldg8_nt(const __hip_bfloat16* p0, const __hip_bfloat16* p1,
                                        short8v* q)
{
    asm volatile(
        "global_load_dwordx4 %0, %8, off nt\n\t"
        "global_load_dwordx4 %1, %8, off offset:64 nt\n\t"
        "global_load_dwordx4 %2, %8, off offset:128 nt\n\t"
        "global_load_dwordx4 %3, %8, off offset:192 nt\n\t"
        "global_load_dwordx4 %4, %9, off nt\n\t"
        "global_load_dwordx4 %5, %9, off offset:64 nt\n\t"
        "global_load_dwordx4 %6, %9, off offset:128 nt\n\t"
        "global_load_dwordx4 %7, %9, off offset:192 nt\n\t"
        "s_waitcnt vmcnt(0)"
        : "=&v"(q[0]), "=&v"(q[1]), "=&v"(q[2]), "=&v"(q[3]),
          "=&v"(q[4]), "=&v"(q[5]), "=&v"(q[6]), "=&v"(q[7])
        : "v"(p0), "v"(p1));
}

// ---- grid barrier: parallel arrivals + distributed release + busy polling ----
__device__ __forceinline__ void gbar(unsigned* flags, unsigned* rel, unsigned& ep)
{
    unsigned tgt = ++ep;
    fence_vm();
    __syncthreads();
    const int tid = threadIdx.x;
    if (blockIdx.x == 0) {
        if (tid > 0) {
            int spins = 0;
            while (ld_coh_u32(&flags[tid * 32]) < tgt) {
                pause_busy();
                if (++spins > (1 << 18)) break;
            }
        }
        __syncthreads();
        st_coh_u32(&rel[tid * 32], tgt);
    } else {
        if (tid == 0) {
            st_coh_u32(&flags[blockIdx.x * 32], tgt);
            int spins = 0;
            while (ld_coh_u32(&rel[blockIdx.x * 32]) < tgt) {
                pause_busy();
                if (++spins > (1 << 18)) break;
            }
        }
        __syncthreads();
    }
}

// ---------- one-time: split+interleave K=1024 weights [Whh|Wih], rows j'=kh*4+g --
__global__ __launch_bounds__(256)
void split_dec_k(const float* __restrict__ Wih, const float* __restrict__ Whh,
                 const float* __restrict__ bsrc,
                 __hip_bfloat16* __restrict__ P0, __hip_bfloat16* __restrict__ P1,
                 __hip_bfloat16* __restrict__ P2, float* __restrict__ bint)
{
    int row = blockIdx.x;
    int l = row >> 11, jp = row & 2047;
    int kh = jp >> 2, g = jp & 3, src = g * 512 + kh;
    const float* wih = Wih + ((size_t)l * 2048 + src) * 512;
    const float* whh = Whh + ((size_t)l * 2048 + src) * 512;
    size_t ro = (size_t)row * 1024;
    for (int k = threadIdx.x; k < 1024; k += 256) {
        float w = (k < 512) ? whh[k] : wih[k - 512];
        __hip_bfloat16 a, b, c2; split3(w, a, b, c2);
        P0[ro + k] = a; P1[ro + k] = b; P2[ro + k] = c2;
    }
    if (threadIdx.x == 0) bint[row] = bsrc[l * 2048 + src];
}

// ---------- one-time: split+interleave encoder layer-0 Whh, K=512 ----------
__global__ __launch_bounds__(256)
void split_enc_k(const float* __restrict__ Whh,
                 __hip_bfloat16* __restrict__ P0, __hip_bfloat16* __restrict__ P1,
                 __hip_bfloat16* __restrict__ P2)
{
    int row = blockIdx.x;
    int kh = row >> 2, g = row & 3, src = g * 512 + kh;
    const float* whh = Whh + (size_t)src * 512;
    size_t ro = (size_t)row * 512;
    for (int k = threadIdx.x; k < 512; k += 256) {
        __hip_bfloat16 a, b, c2; split3(whh[k], a, b, c2);
        P0[ro + k] = a; P1[ro + k] = b; P2[ro + k] = c2;
    }
}

// ---------- f32 GEMM tile (encoder L0 x-part), gate-interleaved coherent store --
__device__ void gemm_tile(char* shraw, const float* __restrict__ A,
                          const float* __restrict__ Wt, const float* __restrict__ bias,
                          float* __restrict__ C,
                          const int* __restrict__ xseq, int m0, int bx, int by)
{
    GemmSh* sh = reinterpret_cast<GemmSh*>(shraw);
    constexpr int K = 512, BK = 16;
    int tid = threadIdx.x;
    int bm = by * 64, bn = bx * 128;
    int tx = tid & 15, ty = tid >> 4;
    float acc[4][8] = {};

    int lm = tid >> 2, lk = (tid & 3) << 2;
    const float* Arow;
    {
        int mg = m0 + bm + lm; int tt = mg >> 6, b = mg & 63;
        Arow = A + (size_t)xseq[b * S + tt] * K;
    }
    int ln = tid >> 1, lkb = (tid & 1) << 3;
    const float* Brow = Wt + (size_t)(bn + ln) * K;

    for (int k0 = 0; k0 < K; k0 += BK) {
        float4 av = *(const float4*)(Arow + k0 + lk);
        sh->As[lk + 0][lm] = av.x; sh->As[lk + 1][lm] = av.y;
        sh->As[lk + 2][lm] = av.z; sh->As[lk + 3][lm] = av.w;
        float4 bv0 = *(const float4*)(Brow + k0 + lkb);
        float4 bv1 = *(const float4*)(Brow + k0 + lkb + 4);
        sh->Bs[lkb + 0][ln] = bv0.x; sh->Bs[lkb + 1][ln] = bv0.y;
        sh->Bs[lkb + 2][ln] = bv0.z; sh->Bs[lkb + 3][ln] = bv0.w;
        sh->Bs[lkb + 4][ln] = bv1.x; sh->Bs[lkb + 5][ln] = bv1.y;
        sh->Bs[lkb + 6][ln] = bv1.z; sh->Bs[lkb + 7][ln] = bv1.w;
        __syncthreads();
#pragma unroll
        for (int kk = 0; kk < BK; ++kk) {
            const float4 a4  = *(const float4*)&sh->As[kk][ty * 4];
            const float4 b4a = *(const float4*)&sh->Bs[kk][tx * 8];
            const float4 b4b = *(const float4*)&sh->Bs[kk][tx * 8 + 4];
            const float a[4]  = {a4.x, a4.y, a4.z, a4.w};
            const float bb[8] = {b4a.x, b4a.y, b4a.z, b4a.w,
                                 b4b.x, b4b.y, b4b.z, b4b.w};
#pragma unroll
            for (int i = 0; i < 4; ++i)
#pragma unroll
                for (int j = 0; j < 8; ++j)
                    acc[i][j] = fmaf(a[i], bb[j], acc[i][j]);
        }
        __syncthreads();
    }
#pragma unroll
    for (int i = 0; i < 4; ++i) {
        size_t crow = (size_t)(bm + ty * 4 + i) * G4;
#pragma unroll
        for (int j = 0; j < 8; ++j) {
            int cg = bn + tx * 8 + j;
            int jp = ((cg & 511) << 2) | (cg >> 9);   // gate-interleave
            st_coh_f32(C + crow + jp, acc[i][j] + bias[cg]);
        }
    }
}

// ---------- LSTM step via 3-way-split bf16 MFMA, THIN blocks, pipelined ---------
// XWAIT: x-half (groups 4..7) gated on 64 per-batch ready-flags (>= need).
template<int KHALF, bool ADDXC, bool MASK, bool XWAIT>
__device__ void step_body(char* shraw, int blk,
    const __hip_bfloat16* __restrict__ hA0, const __hip_bfloat16* __restrict__ hA1,
    const __hip_bfloat16* __restrict__ hA2,
    const __hip_bfloat16* __restrict__ xA0, const __hip_bfloat16* __restrict__ xA1,
    const __hip_bfloat16* __restrict__ xA2,
    const __hip_bfloat16* __restrict__ W0, const __hip_bfloat16* __restrict__ W1,
    const __hip_bfloat16* __restrict__ W2,
    const float* __restrict__ addsrc, const float* __restrict__ h_in,
    float* __restrict__ h_out, float* __restrict__ c,
    __hip_bfloat16* __restrict__ o0, __hip_bfloat16* __restrict__ o1,
    __hip_bfloat16* __restrict__ o2,
    const int* __restrict__ x_len, int t,
    unsigned* __restrict__ xrdy, int need)
{
    StepSh* sh = reinterpret_cast<StepSh*>(shraw);
    int tid = threadIdx.x;
    int wave = tid >> 6, lane = tid & 63;
    int lr = lane & 15, kg = (lane >> 4) * 8;
    int arow = wave * 16 + lr;
    int brow = blk * 16 + lr;
    const int KW = 512 * KHALF;
    constexpr int NG = KHALF * 4;

    f32x4 acc0 = {0,0,0,0}, acc1 = {0,0,0,0}, acc2 = {0,0,0,0};
    const size_t aoff = (size_t)arow * 512 + kg;
    const size_t boff = (size_t)brow * KW + kg;

    auto ap = [&](int g, int pl) -> const __hip_bfloat16* {
        const __hip_bfloat16* base;
        if (KHALF == 2 && g >= 4) {
            base = (pl == 0) ? xA0 : (pl == 1) ? xA1 : xA2;
            return base + aoff + (size_t)(g - 4) * 128;
        }
        base = (pl == 0) ? hA0 : (pl == 1) ? hA1 : hA2;
        return base + aoff + (size_t)g * 128;
    };

    short8v q[2][12];
    issue12_nw(ap(0, 0), ap(0, 1), ap(0, 2), q[0]);
#pragma unroll
    for (int g = 0; g < NG; ++g) {
        constexpr bool HASW = (KHALF == 2) && XWAIT;
        bool boundary = HASW && (g == 3);
        if (g + 1 < NG && !boundary) {
            issue12_w12(ap(g + 1, 0), ap(g + 1, 1), ap(g + 1, 2), q[(g + 1) & 1]);
            __builtin_amdgcn_sched_barrier(0);
        } else {
            wait_vm0_fence();
        }
#pragma unroll
        for (int j = 0; j < 4; ++j) {
            int k0 = g * 128 + j * 32;
            short8v b0 = *(const short8v*)(W0 + boff + k0);
            short8v b1 = *(const short8v*)(W1 + boff + k0);
            short8v b2 = *(const short8v*)(W2 + boff + k0);
            short8v a0 = q[g & 1][j], a1 = q[g & 1][4 + j], a2 = q[g & 1][8 + j];
            acc0 = __builtin_amdgcn_mfma_f32_16x16x32_bf16(a0, b0, acc0, 0, 0, 0);
            acc1 = __builtin_amdgcn_mfma_f32_16x16x32_bf16(a0, b1, acc1, 0, 0, 0);
            acc2 = __builtin_amdgcn_mfma_f32_16x16x32_bf16(a1, b0, acc2, 0, 0, 0);
            acc0 = __builtin_amdgcn_mfma_f32_16x16x32_bf16(a1, b1, acc0, 0, 0, 0);
            acc1 = __builtin_amdgcn_mfma_f32_16x16x32_bf16(a0, b2, acc1, 0, 0, 0);
            acc2 = __builtin_amdgcn_mfma_f32_16x16x32_bf16(a2, b0, acc2, 0, 0, 0);
        }
        if (boundary) {
            // wait for all 64 reduce blocks to publish xP (expected: already done)
            if (tid < 64) {
                int spins = 0;
                while ((int)ld_coh_u32(xrdy + tid * 32) < need) {
                    pause_busy();
                    if (++spins > (1 << 18)) break;
                }
            }
            __syncthreads();
            issue12_nw(ap(4, 0), ap(4, 1), ap(4, 2), q[0]);   // prologue for x-half
        }
    }
    int rb = (lane >> 4) * 4;
#pragma unroll
    for (int r = 0; r < 4; ++r)
        sh->gs[wave * 16 + rb + r][lr] = acc0[r] + acc1[r] + acc2[r];
    __syncthreads();

    int b = tid >> 2, khl = tid & 3;
    int khg = blk * 4 + khl;
    f32x4 add;
    if (ADDXC) add = ld_coh_f32x4(addsrc + (size_t)b * G4 + (size_t)khg * 4);
    else       add = *(const f32x4*)(addsrc + (size_t)khg * 4);
    float gi = sh->gs[b][khl * 4 + 0] + add[0];
    float gf = sh->gs[b][khl * 4 + 1] + add[1];
    float gg = sh->gs[b][khl * 4 + 2] + add[2];
    float go2 = sh->gs[b][khl * 4 + 3] + add[3];
    size_t idx = (size_t)b * H + khg;
    float cold = ld_coh_f32(c + idx);
    float c2 = sigf(gf) * cold + sigf(gi) * tanhf(gg);
    float h2 = sigf(go2) * tanhf(c2);
    if (MASK) {
        bool mk = t < x_len[b];
        if (!mk) { h2 = ld_coh_f32(h_in + idx); c2 = cold; }
    }
    if (h_out) st_coh_f32(h_out + idx, h2);
    st_coh_f32(c + idx, c2);
    __hip_bfloat16 s0, s1, s2; split3(h2, s0, s1, s2);
    st_coh_b16(o0 + idx, s0); st_coh_b16(o1 + idx, s1); st_coh_b16(o2 + idx, s2);
}

// ---------- generator tile: A coherent, Wbf via NT-cached loads -----------------
__device__ void gen_body(char* shraw, int bid,
                         const __hip_bfloat16* __restrict__ hbf,
                         const __hip_bfloat16* __restrict__ Wbf,
                         const float* __restrict__ genb,
                         float* __restrict__ part)
{
    GenSh* sh = reinterpret_cast<GenSh*>(shraw);
    int tid = threadIdx.x;
    int wave = tid >> 6, lane = tid & 63;
    int n0 = bid * NT;
    int lr = lane & 15;
    int kg = (lane >> 4) * 8;

    f32x4 acc[4][2];
    const f32x4 zero = {0.f, 0.f, 0.f, 0.f};
#pragma unroll
    for (int i = 0; i < 4; ++i)
#pragma unroll
        for (int j = 0; j < 2; ++j) acc[i][j] = zero;

    const __hip_bfloat16* Arow = hbf + (size_t)lr * 512 + kg;
    const __hip_bfloat16* Brow = Wbf + (size_t)(n0 + wave * 32 + lr) * 512 + kg;
#pragma unroll
    for (int g = 0; g < 4; ++g) {
        short8v qa[16], qb[8];
        ldg16(Arow + g * 128, Arow + 8192 + g * 128,
              Arow + 16384 + g * 128, Arow + 24576 + g * 128, qa);
        ldg8_nt(Brow + g * 128, Brow + 8192 + g * 128, qb);
#pragma unroll
        for (int j = 0; j < 4; ++j) {
#pragma unroll
            for (int mf = 0; mf < 4; ++mf)
#pragma unroll
                for (int nf = 0; nf < 2; ++nf)
                    acc[mf][nf] = __builtin_amdgcn_mfma_f32_16x16x32_bf16(
                        qa[mf * 4 + j], qb[nf * 4 + j], acc[mf][nf], 0, 0, 0);
        }
    }
#pragma unroll
    for (int nf = 0; nf < 2; ++nf) {
        int colLocal = wave * 32 + nf * 16 + lr;
        float bias = genb[n0 + colLocal];
#pragma unroll
        for (int mf = 0; mf < 4; ++mf) {
#pragma unroll
            for (int r = 0; r < 4; ++r) {
                int row = mf * 16 + (lane >> 4) * 4 + r;
                sh->lds[row][colLocal] = acc[mf][nf][r] + bias;
            }
        }
    }
    __syncthreads();

    int row = tid >> 2, q = tid & 3;
    int cbase = q * 32;
    float v1 = -3.4e38f, v2 = -3.4e38f; int i1 = 0x7fffffff, i2 = 0x7fffffff;
    for (int c = 0; c < 32; ++c) {
        float v = sh->lds[row][cbase + c];
        int ci = cbase + c;
        if (v > v1 || (v == v1 && ci < i1)) { v2 = v1; i2 = i1; v1 = v; i1 = ci; }
        else if (v > v2 || (v == v2 && ci < i2)) { v2 = v; i2 = ci; }
    }
    sh->pv1[row][q] = v1; sh->pi1[row][q] = i1; sh->pv2[row][q] = v2; sh->pi2[row][q] = i2;
    __syncthreads();

    float t1 = -3.4e38f, t2 = -3.4e38f; int j1 = 0x7fffffff, j2 = 0x7fffffff;
    if (q == 0) {
        for (int k = 0; k < 4; ++k) {
            float a1 = sh->pv1[row][k]; int a1i = sh->pi1[row][k];
            float a2 = sh->pv2[row][k]; int a2i = sh->pi2[row][k];
            if (a1 > t1 || (a1 == t1 && a1i < j1)) { t2 = t1; j2 = j1; t1 = a1; j1 = a1i; }
            else if (a1 > t2 || (a1 == t2 && a1i < j2)) { t2 = a1; j2 = a1i; }
            if (a2 > t1 || (a2 == t1 && a2i < j1)) { t2 = t1; j2 = j1; t1 = a2; j1 = a2i; }
            else if (a2 > t2 || (a2 == t2 && a2i < j2)) { t2 = a2; j2 = a2i; }
        }
        sh->mrow[row] = t1;
    }
    __syncthreads();
    float m = sh->mrow[row];
    float s = 0.f;
    for (int c = 0; c < 32; ++c) s += expf(sh->lds[row][cbase + c] - m);
    sh->psum[row][q] = s;
    __syncthreads();
    if (q == 0) {
        float sum = sh->psum[row][0] + sh->psum[row][1] + sh->psum[row][2] + sh->psum[row][3];
        float* p = part + ((size_t)bid * B + row) * 6;
        st_coh_f32(p + 0, t1);
        st_coh_f32(p + 1, t2);
        st_coh_u32((unsigned*)(p + 2), (unsigned)(n0 + j1));
        st_coh_u32((unsigned*)(p + 3), (unsigned)(n0 + j2));
        st_coh_f32(p + 4, sum);
    }
}

// ---------- reduce: combine partials, exact-f32 argmax + gold, emit x-splits ----
// Publishes xrdy[b] = t+1 after xP stores are LLC-visible (if xrdy != nullptr).
__device__ void reduce_body(char* shraw, int b,
                            const float* __restrict__ part,
                            const float* __restrict__ h,
                            const float* __restrict__ genW, const float* __restrict__ genb,
                            const float* __restrict__ tgt_emb,
                            const int* __restrict__ y_seqs, const int* __restrict__ teacher,
                            float* __restrict__ outp,
                            __hip_bfloat16* __restrict__ xp0, __hip_bfloat16* __restrict__ xp1,
                            __hip_bfloat16* __restrict__ xp2, int t,
                            unsigned* __restrict__ xrdy)
{
    RedSh* sh = reinterpret_cast<RedSh*>(shraw);
    int tid = threadIdx.x;
    int y = y_seqs[b * T + t + 1];
    const float* hrow = h + (size_t)b * 512;
    float h_a = ld_coh_f32(hrow + tid);
    float h_b = ld_coh_f32(hrow + tid + 256);

    float p_top1 = -3.4e38f, p_top2 = -3.4e38f, p_sum = 0.f;
    int p_i1 = 0x7fffffff, p_i2 = 0x7fffffff;
    if (tid < NTILES) {
        const float* p = part + ((size_t)tid * B + b) * 6;
        f32x4 v4 = ld_coh_f32x4(p);
        p_top1 = v4[0]; p_top2 = v4[1];
        p_i1 = __float_as_int(v4[2]);
        p_i2 = __float_as_int(v4[3]);
        p_sum = ld_coh_f32(p + 4);
    }
    sh->sM[tid] = p_top1; __syncthreads();
    for (int o = 128; o; o >>= 1) { if (tid < o) sh->sM[tid] = fmaxf(sh->sM[tid], sh->sM[tid + o]); __syncthreads(); }
    float M = sh->sM[0];
    if (tid == 0) sh->cN = 0;
    __syncthreads();

    float Ssum = (tid < NTILES) ? p_sum * expf(p_top1 - M) : 0.f;
    if (tid < NTILES) {
        if (p_top1 >= M - MARGIN) { int j = atomicAdd(&sh->cN, 1); if (j < 16) { sh->cV[j] = p_top1; sh->cI[j] = p_i1; } }
        if (p_top2 >= M - MARGIN) { int j = atomicAdd(&sh->cN, 1); if (j < 16) { sh->cV[j] = p_top2; sh->cI[j] = p_i2; } }
    }
    sh->sS[tid] = Ssum; __syncthreads();
    for (int o = 128; o; o >>= 1) { if (tid < o) sh->sS[tid] += sh->sS[tid + o]; __syncthreads(); }
    float lse = M + logf(sh->sS[0]);
    int nc = sh->cN < 16 ? sh->cN : 16;

    {
        const float* wrow = genW + (size_t)y * 512;
        float s = fmaf(h_a, wrow[tid], 0.f) + h_b * wrow[tid + 256];
        sh->red[tid] = s; __syncthreads();
        for (int o = 128; o; o >>= 1) { if (tid < o) sh->red[tid] += sh->red[tid + o]; __syncthreads(); }
        if (tid == 0) outp[b * TM1 + t] = sh->red[0] + genb[y] - lse;
        __syncthreads();
    }
    if (nc > 1) {
        for (int j = 0; j < nc; ++j) {
            const float* wrow = genW + (size_t)sh->cI[j] * 512;
            float s = fmaf(h_a, wrow[tid], 0.f) + h_b * wrow[tid + 256];
            sh->red[tid] = s; __syncthreads();
            for (int o = 128; o; o >>= 1) { if (tid < o) sh->red[tid] += sh->red[tid + o]; __syncthreads(); }
            if (tid == 0) sh->rV[j] = sh->red[0] + genb[sh->cI[j]];
            __syncthreads();
        }
    }
    if (tid == 0) {
        int winner;
        if (nc == 1) winner = sh->cI[0];
        else {
            float bv = -3.4e38f; int bi = 0x7fffffff;
            for (int j = 0; j < nc; ++j)
                if (sh->rV[j] > bv || (sh->rV[j] == bv && sh->cI[j] < bi)) { bv = sh->rV[j]; bi = sh->cI[j]; }
            winner = bi;
        }
        sh->nxt = (teacher[t] > 0) ? y : winner;
    }
    __syncthreads();
    int tok = sh->nxt;
    for (int k = tid; k < 512; k += 256) {
        float w = tgt_emb[(size_t)tok * 512 + k];
        __hip_bfloat16 s0, s1, s2; split3(w, s0, s1, s2);
        st_coh_b16(xp0 + (size_t)b * 512 + k, s0);
        st_coh_b16(xp1 + (size_t)b * 512 + k, s1);
        st_coh_b16(xp2 + (size_t)b * 512 + k, s2);
    }
    fence_vm();
    __syncthreads();
    if (tid == 0 && xrdy) st_coh_u32(xrdy + b * 32, (unsigned)(t + 1));
}

// ---------- the whole network in one persistent kernel --------------------------
struct Args {
    const int *x_seqs, *x_len, *y_seqs, *teacher;
    const float *src_emb, *tgt_emb, *eWih, *eb, *genW, *genb;
    float* Xc;
    const __hip_bfloat16 *eP0, *eP1, *eP2;
    const __hip_bfloat16 *e1P0, *e1P1, *e1P2;
    const float* ebint;
    const __hip_bfloat16 *dP0, *dP1, *dP2;
    const float* bint;
    float *hf32, *cbuf, *dech1;
    __hip_bfloat16 *P, *xP, *Wbf;
    float* part;
    float* outp;
    unsigned *flags, *rel, *xrdy;
};

__global__ __launch_bounds__(256, 1)
void persist_k(Args a)
{
    __shared__ __align__(16) char shpool[40960];
    unsigned ep = 0;
    const int bid = blockIdx.x;
    const int tid = threadIdx.x;
    const int gtid = bid * 256 + tid;
    const int GS = NBLK * 256;

    auto Pl = [&](int l, int slot, int pl) {
        return a.P + (((size_t)(l * 2 + slot)) * 3 + pl) * BH; };

    // ---- init: zero slot-0 state + c (coherent) ----
    for (int i = gtid; i < BH; i += GS) {
        st_coh_f32(a.hf32 + i, 0.f); st_coh_f32(a.hf32 + 2 * BH + i, 0.f);
        st_coh_f32(a.cbuf + i, 0.f); st_coh_f32(a.cbuf + BH + i, 0.f);
    }
    {
        unsigned* p0 = (unsigned*)Pl(0, 0, 0);
        unsigned* p1 = (unsigned*)Pl(1, 0, 0);
        for (int i = gtid; i < 3 * BH / 2; i += GS) { st_coh_u32(p0 + i, 0u); st_coh_u32(p1 + i, 0u); }
    }
    gbar(a.flags, a.rel, ep);

    // ---- encoder: L0/L1 pipelined (phase t: L0 step t | L1 step t-1) ----
    for (int c0 = 0; c0 < S; c0 += CHUNK) {
        for (int tile = bid; tile < 512; tile += NBLK)
            gemm_tile(shpool, a.src_emb, a.eWih, a.eb, a.Xc,
                      a.x_seqs, c0 * B, tile & 15, tile >> 4);
        gbar(a.flags, a.rel, ep);
        for (int tl = 0; tl < CHUNK; ++tl) {
            int t = c0 + tl;
            if (bid < 128) {
                step_body<1, true, true, false>(shpool, bid,
                    Pl(0, t & 1, 0), Pl(0, t & 1, 1), Pl(0, t & 1, 2),
                    nullptr, nullptr, nullptr,
                    a.eP0, a.eP1, a.eP2,
                    a.Xc + (size_t)tl * B * G4,
                    a.hf32 + (size_t)(t & 1) * BH, a.hf32 + (size_t)((t + 1) & 1) * BH,
                    a.cbuf,
                    Pl(0, (t + 1) & 1, 0), Pl(0, (t + 1) & 1, 1), Pl(0, (t + 1) & 1, 2),
                    a.x_len, t, nullptr, 0);
            } else if (t >= 1) {
                int u = t - 1;
                step_body<2, false, true, false>(shpool, bid - 128,
                    Pl(1, u & 1, 0), Pl(1, u & 1, 1), Pl(1, u & 1, 2),
                    Pl(0, t & 1, 0), Pl(0, t & 1, 1), Pl(0, t & 1, 2),
                    a.e1P0, a.e1P1, a.e1P2,
                    a.ebint,
                    a.hf32 + (size_t)(2 + (u & 1)) * BH, a.hf32 + (size_t)(2 + ((u + 1) & 1)) * BH,
                    a.cbuf + BH,
                    Pl(1, (u + 1) & 1, 0), Pl(1, (u + 1) & 1, 1), Pl(1, (u + 1) & 1, 2),
                    a.x_len, u, nullptr, 0);
            }
            gbar(a.flags, a.rel, ep);
        }
    }
    if (bid < 128) {           // drain: L1 step 127
        int u = S - 1;
        step_body<2, false, true, false>(shpool, bid,
            Pl(1, u & 1, 0), Pl(1, u & 1, 1), Pl(1, u & 1, 2),
            Pl(0, (u + 1) & 1, 0), Pl(0, (u + 1) & 1, 1), Pl(0, (u + 1) & 1, 2),
            a.e1P0, a.e1P1, a.e1P2,
            a.ebint,
            a.hf32 + (size_t)(2 + (u & 1)) * BH, a.hf32 + (size_t)(2 + ((u + 1) & 1)) * BH,
            a.cbuf + BH,
            Pl(1, (u + 1) & 1, 0), Pl(1, (u + 1) & 1, 1), Pl(1, (u + 1) & 1, 2),
            a.x_len, u, nullptr, 0);
    }
    gbar(a.flags, a.rel, ep);

    // ---- genW -> bf16 (fresh region) + BOS x-splits ----
    {
        const int N8 = V * E / 8;
        for (int i = gtid; i < N8; i += GS) {
            float4 x = *(const float4*)(a.genW + (size_t)i * 8);
            float4 y = *(const float4*)(a.genW + (size_t)i * 8 + 4);
            __hip_bfloat16 tmp[8];
            tmp[0] = __float2bfloat16(x.x); tmp[1] = __float2bfloat16(x.y);
            tmp[2] = __float2bfloat16(x.z); tmp[3] = __float2bfloat16(x.w);
            tmp[4] = __float2bfloat16(y.x); tmp[5] = __float2bfloat16(y.y);
            tmp[6] = __float2bfloat16(y.z); tmp[7] = __float2bfloat16(y.w);
            st_coh_b128(a.Wbf + (size_t)i * 8, *(const short8v*)tmp);
        }
        for (int i = gtid; i < BH; i += GS) {
            int k = i & 511;
            float w = a.tgt_emb[512 + k];          // BOS token = 1
            __hip_bfloat16 s0, s1, s2; split3(w, s0, s1, s2);
            st_coh_b16(a.xP + i, s0);
            st_coh_b16(a.xP + BH + i, s1);
            st_coh_b16(a.xP + 2 * BH + i, s2);
        }
    }
    gbar(a.flags, a.rel, ep);

    // ---- decoder: 3 phases/step; reduce(t-1) overlaps L0(t) via x-ready flags ----
    for (int t = 0; t < TM1; ++t) {
        int si = t & 1, so = si ^ 1;
        // Phase A: L0(t) on 0..127 (x-half flag-gated) || reduce(t-1) on 128..191
        if (bid < 128)
            step_body<2, false, false, true>(shpool, bid,
                Pl(0, si, 0), Pl(0, si, 1), Pl(0, si, 2),
                a.xP, a.xP + BH, a.xP + 2 * BH,
                a.dP0, a.dP1, a.dP2, a.bint,
                nullptr, nullptr, a.cbuf,
                Pl(0, so, 0), Pl(0, so, 1), Pl(0, so, 2),
                nullptr, 0, a.xrdy, t);
        else if (bid < 192 && t >= 1)
            reduce_body(shpool, bid - 128, a.part, a.dech1, a.genW, a.genb, a.tgt_emb,
                        a.y_seqs, a.teacher, a.outp,
                        a.xP, a.xP + BH, a.xP + 2 * BH, t - 1, a.xrdy);
        gbar(a.flags, a.rel, ep);
        // Phase B: L1(t)
        if (bid < 128)
            step_body<2, false, false, false>(shpool, bid,
                Pl(1, si, 0), Pl(1, si, 1), Pl(1, si, 2),
                Pl(0, so, 0), Pl(0, so, 1), Pl(0, so, 2),
                a.dP0 + (size_t)G4 * 1024, a.dP1 + (size_t)G4 * 1024,
                a.dP2 + (size_t)G4 * 1024, a.bint + G4,
                nullptr, a.dech1, a.cbuf + BH,
                Pl(1, so, 0), Pl(1, so, 1), Pl(1, so, 2),
                nullptr, 0, nullptr, 0);
        gbar(a.flags, a.rel, ep);
        // Phase C: gen(t)
        if (bid < NTILES)
            gen_body(shpool, bid, Pl(1, so, 0), a.Wbf, a.genb, a.part);
        gbar(a.flags, a.rel, ep);
    }
    // final reduce for t = TM1-1 (no flag publication needed)
    if (bid >= 128 && bid < 192)
        reduce_body(shpool, bid - 128, a.part, a.dech1, a.genW, a.genb, a.tgt_emb,
                    a.y_seqs, a.teacher, a.outp,
                    a.xP, a.xP + BH, a.xP + 2 * BH, TM1 - 1, nullptr);
}

} // namespace

extern "C" void kernel_launch(void* const* d_in, const int* in_sizes, int n_in,
                              void* d_out, int out_size, void* d_ws, size_t ws_size,
                              hipStream_t stream)
{
    (void)in_sizes; (void)n_in; (void)out_size;
    const int*   x_seqs  = (const int*)  d_in[0];
    const int*   x_len   = (const int*)  d_in[1];
    const int*   y_seqs  = (const int*)  d_in[2];
    const int*   teacher = (const int*)  d_in[3];
    const float* src_emb = (const float*)d_in[4];
    const float* tgt_emb = (const float*)d_in[5];
    const float* eWih    = (const float*)d_in[6];
    const float* eWhh    = (const float*)d_in[7];
    const float* eb      = (const float*)d_in[8];
    const float* dWih    = (const float*)d_in[9];
    const float* dWhh    = (const float*)d_in[10];
    const float* db      = (const float*)d_in[11];
    const float* genW    = (const float*)d_in[12];
    const float* genb    = (const float*)d_in[13];

    float* w = (float*)d_ws;
    size_t off = 0;
    auto take = [&](size_t n) { float* p = w + off; off += n; return p; };
    auto takeb = [&](size_t n) { return (__hip_bfloat16*)take((n + 1) / 2); };

    unsigned* flags = (unsigned*)take(256 * 32);
    unsigned* rel   = (unsigned*)take(256 * 32);
    unsigned* xrdy  = (unsigned*)take(64 * 32);
    float* Xc = take((size_t)CHUNK * B * G4);                     // 16.78 MB
    __hip_bfloat16* eP0  = takeb((size_t)G4 * 512);
    __hip_bfloat16* eP1  = takeb((size_t)G4 * 512);
    __hip_bfloat16* eP2  = takeb((size_t)G4 * 512);
    __hip_bfloat16* e1P0 = takeb((size_t)G4 * 1024);
    __hip_bfloat16* e1P1 = takeb((size_t)G4 * 1024);
    __hip_bfloat16* e1P2 = takeb((size_t)G4 * 1024);
    float* ebint = take((size_t)G4);
    __hip_bfloat16* dP0 = takeb((size_t)2 * G4 * 1024);
    __hip_bfloat16* dP1 = takeb((size_t)2 * G4 * 1024);
    __hip_bfloat16* dP2 = takeb((size_t)2 * G4 * 1024);
    float* bint  = take(2 * (size_t)G4);
    float* hf32  = take(4 * (size_t)BH);
    float* cbuf  = take(2 * (size_t)BH);
    float* dech1 = take((size_t)BH);
    __hip_bfloat16* P  = takeb((size_t)12 * BH);
    __hip_bfloat16* xP = takeb((size_t)3 * BH);
    float* part_f = take((size_t)NTILES * B * 6);
    // FRESH Wbf region (32.8MB): never cached-accessed -> nt reads are safe
    __hip_bfloat16* Wbf = takeb((size_t)V * E);
    if (ws_size < off * sizeof(float)) return;    // fail visibly if ws too small

    dim3 tpb256(256);
    split_enc_k<<<dim3(G4), tpb256, 0, stream>>>(eWhh, eP0, eP1, eP2);
    split_dec_k<<<dim3(G4), tpb256, 0, stream>>>(
        eWih + (size_t)G4 * E, eWhh + (size_t)G4 * E, eb + G4, e1P0, e1P1, e1P2, ebint);
    split_dec_k<<<dim3(2 * G4), tpb256, 0, stream>>>(
        dWih, dWhh, db, dP0, dP1, dP2, bint);
    hipError_t _e = hipMemsetAsync(flags, 0, (2 * 256 + 64) * 32 * sizeof(unsigned), stream);
    (void)_e;

    Args a;
    a.x_seqs = x_seqs; a.x_len = x_len; a.y_seqs = y_seqs; a.teacher = teacher;
    a.src_emb = src_emb; a.tgt_emb = tgt_emb; a.eWih = eWih; a.eb = eb;
    a.genW = genW; a.genb = genb;
    a.Xc = Xc;
    a.eP0 = eP0; a.eP1 = eP1; a.eP2 = eP2;
    a.e1P0 = e1P0; a.e1P1 = e1P1; a.e1P2 = e1P2; a.ebint = ebint;
    a.dP0 = dP0; a.dP1 = dP1; a.dP2 = dP2; a.bint = bint;
    a.hf32 = hf32; a.cbuf = cbuf; a.dech1 = dech1;
    a.P = P; a.xP = xP;
    a.Wbf = Wbf;
    a.part = part_f;
    a.outp = (float*)d_out;
    a.flags = flags; a.rel = rel; a.xrdy = xrdy;

    persist_k<<<dim3(NBLK), tpb256, 0, stream>>>(a);
}

// Round 18
// 9387.205 us; speedup vs baseline: 1.1241x; 1.0031x over previous
//
#include <hip/hip_runtime.h>
#include <hip/hip_bf16.h>
#include <cstdint>
#include <cstddef>

namespace {

constexpr int B = 64, S = 128, T = 64, V = 32000, E = 512, H = 512;
constexpr int G4 = 2048;
constexpr int TM1 = T - 1;
constexpr int CHUNK = 32;
constexpr int BH = B * H;           // 32768
constexpr int NT = 128;             // generator N-tile
constexpr int NTILES = V / NT;      // 250
constexpr float MARGIN = 0.02f;
constexpr unsigned NBLK = 256;      // persistent grid (1 block/CU, co-resident)

typedef __attribute__((ext_vector_type(8))) short short8v;
typedef __attribute__((ext_vector_type(4))) float f32x4;

struct GemmSh { float As[16][68]; float Bs[16][132]; };
struct StepSh { float gs[64][17]; };
struct GenSh  { float lds[64][NT + 4]; float pv1[64][4], pv2[64][4], psum[64][4], mrow[64];
                int pi1[64][4], pi2[64][4]; };
struct RedSh  { float sM[256], sS[256], red[256]; float cV[16], rV[16]; int cI[16]; int cN, nxt; };

__device__ __forceinline__ float sigf(float x) { return 1.0f / (1.0f + expf(-x)); }

__device__ __forceinline__ void split3(float w, __hip_bfloat16& a, __hip_bfloat16& b,
                                       __hip_bfloat16& c2) {
    a = __float2bfloat16(w);
    float r = w - __bfloat162float(a);
    b = __float2bfloat16(r);
    c2 = __float2bfloat16(r - __bfloat162float(b));
}

// ================= LLC-coherent (sc0 sc1) access primitives =================
__device__ __forceinline__ unsigned ld_coh_u32(const unsigned* p) {
    unsigned v;
    asm volatile("global_load_dword %0, %1, off sc0 sc1\n\ts_waitcnt vmcnt(0)"
                 : "=v"(v) : "v"(p) : "memory");
    return v;
}
__device__ __forceinline__ void st_coh_u32(unsigned* p, unsigned v) {
    asm volatile("global_store_dword %0, %1, off sc0 sc1" :: "v"(p), "v"(v) : "memory");
}
__device__ __forceinline__ float ld_coh_f32(const float* p) {
    float v;
    asm volatile("global_load_dword %0, %1, off sc0 sc1\n\ts_waitcnt vmcnt(0)"
                 : "=v"(v) : "v"(p));
    return v;
}
__device__ __forceinline__ void st_coh_f32(float* p, float v) {
    asm volatile("global_store_dword %0, %1, off sc0 sc1" :: "v"(p), "v"(v));
}
__device__ __forceinline__ f32x4 ld_coh_f32x4(const float* p) {
    f32x4 v;
    asm volatile("global_load_dwordx4 %0, %1, off sc0 sc1\n\ts_waitcnt vmcnt(0)"
                 : "=v"(v) : "v"(p));
    return v;
}
__device__ __forceinline__ void st_coh_b16(__hip_bfloat16* p, __hip_bfloat16 v) {
    unsigned short us; __builtin_memcpy(&us, &v, 2);
    unsigned u = us;
    asm volatile("global_store_short %0, %1, off sc0 sc1" :: "v"(p), "v"(u));
}
__device__ __forceinline__ void st_coh_b128(__hip_bfloat16* p, short8v v) {
    asm volatile("global_store_dwordx4 %0, %1, off sc0 sc1" :: "v"(p), "v"(v));
}
__device__ __forceinline__ void fence_vm() {
    asm volatile("s_waitcnt vmcnt(0)" ::: "memory");
}

// ---- busy pause: short dependent VALU chain between polls ----
__device__ __forceinline__ void pause_busy() {
    float x = 1.0f;
#pragma unroll
    for (int i = 0; i < 48; ++i)
        asm volatile("v_fmac_f32 %0, %1, %1" : "+v"(x) : "v"(1.0000001f));
    asm volatile("" :: "v"(x));
}

// ---- step A-path: 2-deep pipelined coherent load groups -------------------
__device__ __forceinline__ void issue12_nw(const __hip_bfloat16* p0, const __hip_bfloat16* p1,
                                           const __hip_bfloat16* p2, short8v* q)
{
    asm volatile(
        "global_load_dwordx4 %0, %12, off sc0 sc1\n\t"
        "global_load_dwordx4 %1, %12, off offset:64 sc0 sc1\n\t"
        "global_load_dwordx4 %2, %12, off offset:128 sc0 sc1\n\t"
        "global_load_dwordx4 %3, %12, off offset:192 sc0 sc1\n\t"
        "global_load_dwordx4 %4, %13, off sc0 sc1\n\t"
        "global_load_dwordx4 %5, %13, off offset:64 sc0 sc1\n\t"
        "global_load_dwordx4 %6, %13, off offset:128 sc0 sc1\n\t"
        "global_load_dwordx4 %7, %13, off offset:192 sc0 sc1\n\t"
        "global_load_dwordx4 %8, %14, off sc0 sc1\n\t"
        "global_load_dwordx4 %9, %14, off offset:64 sc0 sc1\n\t"
        "global_load_dwordx4 %10, %14, off offset:128 sc0 sc1\n\t"
        "global_load_dwordx4 %11, %14, off offset:192 sc0 sc1"
        : "=&v"(q[0]), "=&v"(q[1]), "=&v"(q[2]), "=&v"(q[3]),
          "=&v"(q[4]), "=&v"(q[5]), "=&v"(q[6]), "=&v"(q[7]),
          "=&v"(q[8]), "=&v"(q[9]), "=&v"(q[10]), "=&v"(q[11])
        : "v"(p0), "v"(p1), "v"(p2));
}
__device__ __forceinline__ void issue12_w12(const __hip_bfloat16* p0, const __hip_bfloat16* p1,
                                            const __hip_bfloat16* p2, short8v* q)
{
    asm volatile(
        "global_load_dwordx4 %0, %12, off sc0 sc1\n\t"
        "global_load_dwordx4 %1, %12, off offset:64 sc0 sc1\n\t"
        "global_load_dwordx4 %2, %12, off offset:128 sc0 sc1\n\t"
        "global_load_dwordx4 %3, %12, off offset:192 sc0 sc1\n\t"
        "global_load_dwordx4 %4, %13, off sc0 sc1\n\t"
        "global_load_dwordx4 %5, %13, off offset:64 sc0 sc1\n\t"
        "global_load_dwordx4 %6, %13, off offset:128 sc0 sc1\n\t"
        "global_load_dwordx4 %7, %13, off offset:192 sc0 sc1\n\t"
        "global_load_dwordx4 %8, %14, off sc0 sc1\n\t"
        "global_load_dwordx4 %9, %14, off offset:64 sc0 sc1\n\t"
        "global_load_dwordx4 %10, %14, off offset:128 sc0 sc1\n\t"
        "global_load_dwordx4 %11, %14, off offset:192 sc0 sc1\n\t"
        "s_waitcnt vmcnt(12)"
        : "=&v"(q[0]), "=&v"(q[1]), "=&v"(q[2]), "=&v"(q[3]),
          "=&v"(q[4]), "=&v"(q[5]), "=&v"(q[6]), "=&v"(q[7]),
          "=&v"(q[8]), "=&v"(q[9]), "=&v"(q[10]), "=&v"(q[11])
        : "v"(p0), "v"(p1), "v"(p2) : "memory");
}
__device__ __forceinline__ void wait_vm0_fence() {
    asm volatile("s_waitcnt vmcnt(0)" ::: "memory");
    __builtin_amdgcn_sched_barrier(0);
}

// 16 coherent loads (4 pointers x 4 k-subtiles) + waitcnt (gen A side).
__device__ __forceinline__ void ldg16(const __hip_bfloat16* p0, const __hip_bfloat16* p1,
                                      const __hip_bfloat16* p2, const __hip_bfloat16* p3,
                                      short8v* q)
{
    asm volatile(
        "global_load_dwordx4 %0, %16, off sc0 sc1\n\t"
        "global_load_dwordx4 %1, %16, off offset:64 sc0 sc1\n\t"
        "global_load_dwordx4 %2, %16, off offset:128 sc0 sc1\n\t"
        "global_load_dwordx4 %3, %16, off offset:192 sc0 sc1\n\t"
        "global_load_dwordx4 %4, %17, off sc0 sc1\n\t"
        "global_load_dwordx4 %5, %17, off offset:64 sc0 sc1\n\t"
        "global_load_dwordx4 %6, %17, off offset:128 sc0 sc1\n\t"
        "global_load_dwordx4 %7, %17, off offset:192 sc0 sc1\n\t"
        "global_load_dwordx4 %8, %18, off sc0 sc1\n\t"
        "global_load_dwordx4 %9, %18, off offset:64 sc0 sc1\n\t"
        "global_load_dwordx4 %10, %18, off offset:128 sc0 sc1\n\t"
        "global_load_dwordx4 %11, %18, off offset:192 sc0 sc1\n\t"
        "global_load_dwordx4 %12, %19, off sc0 sc1\n\t"
        "global_load_dwordx4 %13, %19, off offset:64 sc0 sc1\n\t"
        "global_load_dwordx4 %14, %19, off offset:128 sc0 sc1\n\t"
        "global_load_dwordx4 %15, %19, off offset:192 sc0 sc1\n\t"
        "s_waitcnt vmcnt(0)"
        : "=&v"(q[0]), "=&v"(q[1]), "=&v"(q[2]), "=&v"(q[3]),
          "=&v"(q[4]), "=&v"(q[5]), "=&v"(q[6]), "=&v"(q[7]),
          "=&v"(q[8]), "=&v"(q[9]), "=&v"(q[10]), "=&v"(q[11]),
          "=&v"(q[12]), "=&v"(q[13]), "=&v"(q[14]), "=&v"(q[15])
        : "v"(p0), "v"(p1), "v"(p2), "v"(p3));
}

// 8 NT-cached loads (2 pointers x 4) + waitcnt (gen Wbf side, fresh region).
__device__ __forceinline__ void ldg8_nt(const __hip_bfloat16* p0, const __hip_bfloat16* p1,
                                        short8v* q)
{
    asm volatile(
        "global_load_dwordx4 %0, %8, off nt\n\t"
        "global_load_dwordx4 %1, %8, off offset:64 nt\n\t"
        "global_load_dwordx4 %2, %8, off offset:128 nt\n\t"
        "global_load_dwordx4 %3, %8, off offset:192 nt\n\t"
        "global_load_dwordx4 %4, %9, off nt\n\t"
        "global_load_dwordx4 %5, %9, off offset:64 nt\n\t"
        "global_load_dwordx4 %6, %9, off offset:128 nt\n\t"
        "global_load_dwordx4 %7, %9, off offset:192 nt\n\t"
        "s_waitcnt vmcnt(0)"
        : "=&v"(q[0]), "=&v"(q[1]), "=&v"(q[2]), "=&v"(q[3]),
          "=&v"(q[4]), "=&v"(q[5]), "=&v"(q[6]), "=&v"(q[7])
        : "v"(p0), "v"(p1));
}

// ---- grid barrier: parallel arrivals + distributed release + busy polling ----
__device__ __forceinline__ void gbar(unsigned* flags, unsigned* rel, unsigned& ep)
{
    unsigned tgt = ++ep;
    fence_vm();
    __syncthreads();
    const int tid = threadIdx.x;
    if (blockIdx.x == 0) {
        if (tid > 0) {
            int spins = 0;
            while (ld_coh_u32(&flags[tid * 32]) < tgt) {
                pause_busy();
                if (++spins > (1 << 18)) break;
            }
        }
        __syncthreads();
        st_coh_u32(&rel[tid * 32], tgt);
    } else {
        if (tid == 0) {
            st_coh_u32(&flags[blockIdx.x * 32], tgt);
            int spins = 0;
            while (ld_coh_u32(&rel[blockIdx.x * 32]) < tgt) {
                pause_busy();
                if (++spins > (1 << 18)) break;
            }
        }
        __syncthreads();
    }
}

// ---------- one-time: split+interleave K=1024 weights [Whh|Wih], rows j'=kh*4+g --
__global__ __launch_bounds__(256)
void split_dec_k(const float* __restrict__ Wih, const float* __restrict__ Whh,
                 const float* __restrict__ bsrc,
                 __hip_bfloat16* __restrict__ P0, __hip_bfloat16* __restrict__ P1,
                 __hip_bfloat16* __restrict__ P2, float* __restrict__ bint)
{
    int row = blockIdx.x;
    int l = row >> 11, jp = row & 2047;
    int kh = jp >> 2, g = jp & 3, src = g * 512 + kh;
    const float* wih = Wih + ((size_t)l * 2048 + src) * 512;
    const float* whh = Whh + ((size_t)l * 2048 + src) * 512;
    size_t ro = (size_t)row * 1024;
    for (int k = threadIdx.x; k < 1024; k += 256) {
        float w = (k < 512) ? whh[k] : wih[k - 512];
        __hip_bfloat16 a, b, c2; split3(w, a, b, c2);
        P0[ro + k] = a; P1[ro + k] = b; P2[ro + k] = c2;
    }
    if (threadIdx.x == 0) bint[row] = bsrc[l * 2048 + src];
}

// ---------- one-time: split+interleave encoder layer-0 Whh, K=512 ----------
__global__ __launch_bounds__(256)
void split_enc_k(const float* __restrict__ Whh,
                 __hip_bfloat16* __restrict__ P0, __hip_bfloat16* __restrict__ P1,
                 __hip_bfloat16* __restrict__ P2)
{
    int row = blockIdx.x;
    int kh = row >> 2, g = row & 3, src = g * 512 + kh;
    const float* whh = Whh + (size_t)src * 512;
    size_t ro = (size_t)row * 512;
    for (int k = threadIdx.x; k < 512; k += 256) {
        __hip_bfloat16 a, b, c2; split3(whh[k], a, b, c2);
        P0[ro + k] = a; P1[ro + k] = b; P2[ro + k] = c2;
    }
}

// ---------- f32 GEMM tile (encoder L0 x-part), gate-interleaved coherent store --
__device__ void gemm_tile(char* shraw, const float* __restrict__ A,
                          const float* __restrict__ Wt, const float* __restrict__ bias,
                          float* __restrict__ C,
                          const int* __restrict__ xseq, int m0, int bx, int by)
{
    GemmSh* sh = reinterpret_cast<GemmSh*>(shraw);
    constexpr int K = 512, BK = 16;
    int tid = threadIdx.x;
    int bm = by * 64, bn = bx * 128;
    int tx = tid & 15, ty = tid >> 4;
    float acc[4][8] = {};

    int lm = tid >> 2, lk = (tid & 3) << 2;
    const float* Arow;
    {
        int mg = m0 + bm + lm; int tt = mg >> 6, b = mg & 63;
        Arow = A + (size_t)xseq[b * S + tt] * K;
    }
    int ln = tid >> 1, lkb = (tid & 1) << 3;
    const float* Brow = Wt + (size_t)(bn + ln) * K;

    for (int k0 = 0; k0 < K; k0 += BK) {
        float4 av = *(const float4*)(Arow + k0 + lk);
        sh->As[lk + 0][lm] = av.x; sh->As[lk + 1][lm] = av.y;
        sh->As[lk + 2][lm] = av.z; sh->As[lk + 3][lm] = av.w;
        float4 bv0 = *(const float4*)(Brow + k0 + lkb);
        float4 bv1 = *(const float4*)(Brow + k0 + lkb + 4);
        sh->Bs[lkb + 0][ln] = bv0.x; sh->Bs[lkb + 1][ln] = bv0.y;
        sh->Bs[lkb + 2][ln] = bv0.z; sh->Bs[lkb + 3][ln] = bv0.w;
        sh->Bs[lkb + 4][ln] = bv1.x; sh->Bs[lkb + 5][ln] = bv1.y;
        sh->Bs[lkb + 6][ln] = bv1.z; sh->Bs[lkb + 7][ln] = bv1.w;
        __syncthreads();
#pragma unroll
        for (int kk = 0; kk < BK; ++kk) {
            const float4 a4  = *(const float4*)&sh->As[kk][ty * 4];
            const float4 b4a = *(const float4*)&sh->Bs[kk][tx * 8];
            const float4 b4b = *(const float4*)&sh->Bs[kk][tx * 8 + 4];
            const float a[4]  = {a4.x, a4.y, a4.z, a4.w};
            const float bb[8] = {b4a.x, b4a.y, b4a.z, b4a.w,
                                 b4b.x, b4b.y, b4b.z, b4b.w};
#pragma unroll
            for (int i = 0; i < 4; ++i)
#pragma unroll
                for (int j = 0; j < 8; ++j)
                    acc[i][j] = fmaf(a[i], bb[j], acc[i][j]);
        }
        __syncthreads();
    }
#pragma unroll
    for (int i = 0; i < 4; ++i) {
        size_t crow = (size_t)(bm + ty * 4 + i) * G4;
#pragma unroll
        for (int j = 0; j < 8; ++j) {
            int cg = bn + tx * 8 + j;
            int jp = ((cg & 511) << 2) | (cg >> 9);   // gate-interleave
            st_coh_f32(C + crow + jp, acc[i][j] + bias[cg]);
        }
    }
}

// ---------- LSTM step via 3-way-split bf16 MFMA, THIN blocks, pipelined ---------
// XWAIT: x-half (groups 4..7) gated on 64 per-batch ready-flags (>= need).
template<int KHALF, bool ADDXC, bool MASK, bool XWAIT>
__device__ void step_body(char* shraw, int blk,
    const __hip_bfloat16* __restrict__ hA0, const __hip_bfloat16* __restrict__ hA1,
    const __hip_bfloat16* __restrict__ hA2,
    const __hip_bfloat16* __restrict__ xA0, const __hip_bfloat16* __restrict__ xA1,
    const __hip_bfloat16* __restrict__ xA2,
    const __hip_bfloat16* __restrict__ W0, const __hip_bfloat16* __restrict__ W1,
    const __hip_bfloat16* __restrict__ W2,
    const float* __restrict__ addsrc, const float* __restrict__ h_in,
    float* __restrict__ h_out, float* __restrict__ c,
    __hip_bfloat16* __restrict__ o0, __hip_bfloat16* __restrict__ o1,
    __hip_bfloat16* __restrict__ o2,
    const int* __restrict__ x_len, int t,
    unsigned* __restrict__ xrdy, int need)
{
    StepSh* sh = reinterpret_cast<StepSh*>(shraw);
    int tid = threadIdx.x;
    int wave = tid >> 6, lane = tid & 63;
    int lr = lane & 15, kg = (lane >> 4) * 8;
    int arow = wave * 16 + lr;
    int brow = blk * 16 + lr;
    const int KW = 512 * KHALF;
    constexpr int NG = KHALF * 4;

    f32x4 acc0 = {0,0,0,0}, acc1 = {0,0,0,0}, acc2 = {0,0,0,0};
    const size_t aoff = (size_t)arow * 512 + kg;
    const size_t boff = (size_t)brow * KW + kg;

    auto ap = [&](int g, int pl) -> const __hip_bfloat16* {
        const __hip_bfloat16* base;
        if (KHALF == 2 && g >= 4) {
            base = (pl == 0) ? xA0 : (pl == 1) ? xA1 : xA2;
            return base + aoff + (size_t)(g - 4) * 128;
        }
        base = (pl == 0) ? hA0 : (pl == 1) ? hA1 : hA2;
        return base + aoff + (size_t)g * 128;
    };

    short8v q[2][12];
    issue12_nw(ap(0, 0), ap(0, 1), ap(0, 2), q[0]);
#pragma unroll
    for (int g = 0; g < NG; ++g) {
        constexpr bool HASW = (KHALF == 2) && XWAIT;
        bool boundary = HASW && (g == 3);
        if (g + 1 < NG && !boundary) {
            issue12_w12(ap(g + 1, 0), ap(g + 1, 1), ap(g + 1, 2), q[(g + 1) & 1]);
            __builtin_amdgcn_sched_barrier(0);
        } else {
            wait_vm0_fence();
        }
#pragma unroll
        for (int j = 0; j < 4; ++j) {
            int k0 = g * 128 + j * 32;
            short8v b0 = *(const short8v*)(W0 + boff + k0);
            short8v b1 = *(const short8v*)(W1 + boff + k0);
            short8v b2 = *(const short8v*)(W2 + boff + k0);
            short8v a0 = q[g & 1][j], a1 = q[g & 1][4 + j], a2 = q[g & 1][8 + j];
            acc0 = __builtin_amdgcn_mfma_f32_16x16x32_bf16(a0, b0, acc0, 0, 0, 0);
            acc1 = __builtin_amdgcn_mfma_f32_16x16x32_bf16(a0, b1, acc1, 0, 0, 0);
            acc2 = __builtin_amdgcn_mfma_f32_16x16x32_bf16(a1, b0, acc2, 0, 0, 0);
            acc0 = __builtin_amdgcn_mfma_f32_16x16x32_bf16(a1, b1, acc0, 0, 0, 0);
            acc1 = __builtin_amdgcn_mfma_f32_16x16x32_bf16(a0, b2, acc1, 0, 0, 0);
            acc2 = __builtin_amdgcn_mfma_f32_16x16x32_bf16(a2, b0, acc2, 0, 0, 0);
        }
        if (boundary) {
            // wait for all 64 reduce blocks to publish xP (expected: already done)
            if (tid < 64) {
                int spins = 0;
                while ((int)ld_coh_u32(xrdy + tid * 32) < need) {
                    pause_busy();
                    if (++spins > (1 << 18)) break;
                }
            }
            __syncthreads();
            issue12_nw(ap(4, 0), ap(4, 1), ap(4, 2), q[0]);   // prologue for x-half
        }
    }
    int rb = (lane >> 4) * 4;
#pragma unroll
    for (int r = 0; r < 4; ++r)
        sh->gs[wave * 16 + rb + r][lr] = acc0[r] + acc1[r] + acc2[r];
    __syncthreads();

    int b = tid >> 2, khl = tid & 3;
    int khg = blk * 4 + khl;
    f32x4 add;
    if (ADDXC) add = ld_coh_f32x4(addsrc + (size_t)b * G4 + (size_t)khg * 4);
    else       add = *(const f32x4*)(addsrc + (size_t)khg * 4);
    float gi = sh->gs[b][khl * 4 + 0] + add[0];
    float gf = sh->gs[b][khl * 4 + 1] + add[1];
    float gg = sh->gs[b][khl * 4 + 2] + add[2];
    float go2 = sh->gs[b][khl * 4 + 3] + add[3];
    size_t idx = (size_t)b * H + khg;
    float cold = ld_coh_f32(c + idx);
    float c2 = sigf(gf) * cold + sigf(gi) * tanhf(gg);
    float h2 = sigf(go2) * tanhf(c2);
    if (MASK) {
        bool mk = t < x_len[b];
        if (!mk) { h2 = ld_coh_f32(h_in + idx); c2 = cold; }
    }
    if (h_out) st_coh_f32(h_out + idx, h2);
    st_coh_f32(c + idx, c2);
    __hip_bfloat16 s0, s1, s2; split3(h2, s0, s1, s2);
    st_coh_b16(o0 + idx, s0); st_coh_b16(o1 + idx, s1); st_coh_b16(o2 + idx, s2);
}

// ---------- generator tile: A coherent, Wbf via NT-cached loads -----------------
__device__ void gen_body(char* shraw, int bid,
                         const __hip_bfloat16* __restrict__ hbf,
                         const __hip_bfloat16* __restrict__ Wbf,
                         const float* __restrict__ genb,
                         float* __restrict__ part)
{
    GenSh* sh = reinterpret_cast<GenSh*>(shraw);
    int tid = threadIdx.x;
    int wave = tid >> 6, lane = tid & 63;
    int n0 = bid * NT;
    int lr = lane & 15;
    int kg = (lane >> 4) * 8;

    f32x4 acc[4][2];
    const f32x4 zero = {0.f, 0.f, 0.f, 0.f};
#pragma unroll
    for (int i = 0; i < 4; ++i)
#pragma unroll
        for (int j = 0; j < 2; ++j) acc[i][j] = zero;

    const __hip_bfloat16* Arow = hbf + (size_t)lr * 512 + kg;
    const __hip_bfloat16* Brow = Wbf + (size_t)(n0 + wave * 32 + lr) * 512 + kg;
#pragma unroll
    for (int g = 0; g < 4; ++g) {
        short8v qa[16], qb[8];
        ldg16(Arow + g * 128, Arow + 8192 + g * 128,
              Arow + 16384 + g * 128, Arow + 24576 + g * 128, qa);
        ldg8_nt(Brow + g * 128, Brow + 8192 + g * 128, qb);
#pragma unroll
        for (int j = 0; j < 4; ++j) {
#pragma unroll
            for (int mf = 0; mf < 4; ++mf)
#pragma unroll
                for (int nf = 0; nf < 2; ++nf)
                    acc[mf][nf] = __builtin_amdgcn_mfma_f32_16x16x32_bf16(
                        qa[mf * 4 + j], qb[nf * 4 + j], acc[mf][nf], 0, 0, 0);
        }
    }
#pragma unroll
    for (int nf = 0; nf < 2; ++nf) {
        int colLocal = wave * 32 + nf * 16 + lr;
        float bias = genb[n0 + colLocal];
#pragma unroll
        for (int mf = 0; mf < 4; ++mf) {
#pragma unroll
            for (int r = 0; r < 4; ++r) {
                int row = mf * 16 + (lane >> 4) * 4 + r;
                sh->lds[row][colLocal] = acc[mf][nf][r] + bias;
            }
        }
    }
    __syncthreads();

    int row = tid >> 2, q = tid & 3;
    int cbase = q * 32;
    float v1 = -3.4e38f, v2 = -3.4e38f; int i1 = 0x7fffffff, i2 = 0x7fffffff;
    for (int c = 0; c < 32; ++c) {
        float v = sh->lds[row][cbase + c];
        int ci = cbase + c;
        if (v > v1 || (v == v1 && ci < i1)) { v2 = v1; i2 = i1; v1 = v; i1 = ci; }
        else if (v > v2 || (v == v2 && ci < i2)) { v2 = v; i2 = ci; }
    }
    sh->pv1[row][q] = v1; sh->pi1[row][q] = i1; sh->pv2[row][q] = v2; sh->pi2[row][q] = i2;
    __syncthreads();

    float t1 = -3.4e38f, t2 = -3.4e38f; int j1 = 0x7fffffff, j2 = 0x7fffffff;
    if (q == 0) {
        for (int k = 0; k < 4; ++k) {
            float a1 = sh->pv1[row][k]; int a1i = sh->pi1[row][k];
            float a2 = sh->pv2[row][k]; int a2i = sh->pi2[row][k];
            if (a1 > t1 || (a1 == t1 && a1i < j1)) { t2 = t1; j2 = j1; t1 = a1; j1 = a1i; }
            else if (a1 > t2 || (a1 == t2 && a1i < j2)) { t2 = a1; j2 = a1i; }
            if (a2 > t1 || (a2 == t1 && a2i < j1)) { t2 = t1; j2 = j1; t1 = a2; j1 = a2i; }
            else if (a2 > t2 || (a2 == t2 && a2i < j2)) { t2 = a2; j2 = a2i; }
        }
        sh->mrow[row] = t1;
    }
    __syncthreads();
    float m = sh->mrow[row];
    float s = 0.f;
    for (int c = 0; c < 32; ++c) s += expf(sh->lds[row][cbase + c] - m);
    sh->psum[row][q] = s;
    __syncthreads();
    if (q == 0) {
        float sum = sh->psum[row][0] + sh->psum[row][1] + sh->psum[row][2] + sh->psum[row][3];
        float* p = part + ((size_t)bid * B + row) * 6;
        st_coh_f32(p + 0, t1);
        st_coh_f32(p + 1, t2);
        st_coh_u32((unsigned*)(p + 2), (unsigned)(n0 + j1));
        st_coh_u32((unsigned*)(p + 3), (unsigned)(n0 + j2));
        st_coh_f32(p + 4, sum);
    }
}

// ---------- reduce: combine partials, exact-f32 argmax + gold, emit x-splits ----
// Publishes xrdy[b] = t+1 after xP stores are LLC-visible (if xrdy != nullptr).
__device__ void reduce_body(char* shraw, int b,
                            const float* __restrict__ part,
                            const float* __restrict__ h,
                            const float* __restrict__ genW, const float* __restrict__ genb,
                            const float* __restrict__ tgt_emb,
                            const int* __restrict__ y_seqs, const int* __restrict__ teacher,
                            float* __restrict__ outp,
                            __hip_bfloat16* __restrict__ xp0, __hip_bfloat16* __restrict__ xp1,
                            __hip_bfloat16* __restrict__ xp2, int t,
                            unsigned* __restrict__ xrdy)
{
    RedSh* sh = reinterpret_cast<RedSh*>(shraw);
    int tid = threadIdx.x;
    int y = y_seqs[b * T + t + 1];
    const float* hrow = h + (size_t)b * 512;
    float h_a = ld_coh_f32(hrow + tid);
    float h_b = ld_coh_f32(hrow + tid + 256);

    float p_top1 = -3.4e38f, p_top2 = -3.4e38f, p_sum = 0.f;
    int p_i1 = 0x7fffffff, p_i2 = 0x7fffffff;
    if (tid < NTILES) {
        const float* p = part + ((size_t)tid * B + b) * 6;
        f32x4 v4 = ld_coh_f32x4(p);
        p_top1 = v4[0]; p_top2 = v4[1];
        p_i1 = __float_as_int(v4[2]);
        p_i2 = __float_as_int(v4[3]);
        p_sum = ld_coh_f32(p + 4);
    }
    sh->sM[tid] = p_top1; __syncthreads();
    for (int o = 128; o; o >>= 1) { if (tid < o) sh->sM[tid] = fmaxf(sh->sM[tid], sh->sM[tid + o]); __syncthreads(); }
    float M = sh->sM[0];
    if (tid == 0) sh->cN = 0;
    __syncthreads();

    float Ssum = (tid < NTILES) ? p_sum * expf(p_top1 - M) : 0.f;
    if (tid < NTILES) {
        if (p_top1 >= M - MARGIN) { int j = atomicAdd(&sh->cN, 1); if (j < 16) { sh->cV[j] = p_top1; sh->cI[j] = p_i1; } }
        if (p_top2 >= M - MARGIN) { int j = atomicAdd(&sh->cN, 1); if (j < 16) { sh->cV[j] = p_top2; sh->cI[j] = p_i2; } }
    }
    sh->sS[tid] = Ssum; __syncthreads();
    for (int o = 128; o; o >>= 1) { if (tid < o) sh->sS[tid] += sh->sS[tid + o]; __syncthreads(); }
    float lse = M + logf(sh->sS[0]);
    int nc = sh->cN < 16 ? sh->cN : 16;

    {
        const float* wrow = genW + (size_t)y * 512;
        float s = fmaf(h_a, wrow[tid], 0.f) + h_b * wrow[tid + 256];
        sh->red[tid] = s; __syncthreads();
        for (int o = 128; o; o >>= 1) { if (tid < o) sh->red[tid] += sh->red[tid + o]; __syncthreads(); }
        if (tid == 0) outp[b * TM1 + t] = sh->red[0] + genb[y] - lse;
        __syncthreads();
    }
    if (nc > 1) {
        for (int j = 0; j < nc; ++j) {
            const float* wrow = genW + (size_t)sh->cI[j] * 512;
            float s = fmaf(h_a, wrow[tid], 0.f) + h_b * wrow[tid + 256];
            sh->red[tid] = s; __syncthreads();
            for (int o = 128; o; o >>= 1) { if (tid < o) sh->red[tid] += sh->red[tid + o]; __syncthreads(); }
            if (tid == 0) sh->rV[j] = sh->red[0] + genb[sh->cI[j]];
            __syncthreads();
        }
    }
    if (tid == 0) {
        int winner;
        if (nc == 1) winner = sh->cI[0];
        else {
            float bv = -3.4e38f; int bi = 0x7fffffff;
            for (int j = 0; j < nc; ++j)
                if (sh->rV[j] > bv || (sh->rV[j] == bv && sh->cI[j] < bi)) { bv = sh->rV[j]; bi = sh->cI[j]; }
            winner = bi;
        }
        sh->nxt = (teacher[t] > 0) ? y : winner;
    }
    __syncthreads();
    int tok = sh->nxt;
    for (int k = tid; k < 512; k += 256) {
        float w = tgt_emb[(size_t)tok * 512 + k];
        __hip_bfloat16 s0, s1, s2; split3(w, s0, s1, s2);
        st_coh_b16(xp0 + (size_t)b * 512 + k, s0);
        st_coh_b16(xp1 + (size_t)b * 512 + k, s1);
        st_coh_b16(xp2 + (size_t)b * 512 + k, s2);
    }
    fence_vm();
    __syncthreads();
    if (tid == 0 && xrdy) st_coh_u32(xrdy + b * 32, (unsigned)(t + 1));
}

// ---------- the whole network in one persistent kernel --------------------------
struct Args {
    const int *x_seqs, *x_len, *y_seqs, *teacher;
    const float *src_emb, *tgt_emb, *eWih, *eb, *genW, *genb;
    float* Xc;
    const __hip_bfloat16 *eP0, *eP1, *eP2;
    const __hip_bfloat16 *e1P0, *e1P1, *e1P2;
    const float* ebint;
    const __hip_bfloat16 *dP0, *dP1, *dP2;
    const float* bint;
    float *hf32, *cbuf, *dech1;
    __hip_bfloat16 *P, *xP, *Wbf;
    float* part;
    float* outp;
    unsigned *flags, *rel, *xrdy;
};

__global__ __launch_bounds__(256, 1)
void persist_k(Args a)
{
    __shared__ __align__(16) char shpool[40960];
    unsigned ep = 0;
    const int bid = blockIdx.x;
    const int tid = threadIdx.x;
    const int gtid = bid * 256 + tid;
    const int GS = NBLK * 256;

    auto Pl = [&](int l, int slot, int pl) {
        return a.P + (((size_t)(l * 2 + slot)) * 3 + pl) * BH; };

    // ---- init: zero slot-0 state + c (coherent) ----
    for (int i = gtid; i < BH; i += GS) {
        st_coh_f32(a.hf32 + i, 0.f); st_coh_f32(a.hf32 + 2 * BH + i, 0.f);
        st_coh_f32(a.cbuf + i, 0.f); st_coh_f32(a.cbuf + BH + i, 0.f);
    }
    {
        unsigned* p0 = (unsigned*)Pl(0, 0, 0);
        unsigned* p1 = (unsigned*)Pl(1, 0, 0);
        for (int i = gtid; i < 3 * BH / 2; i += GS) { st_coh_u32(p0 + i, 0u); st_coh_u32(p1 + i, 0u); }
    }
    gbar(a.flags, a.rel, ep);

    // ---- encoder: L0/L1 pipelined (phase t: L0 step t | L1 step t-1) ----
    for (int c0 = 0; c0 < S; c0 += CHUNK) {
        for (int tile = bid; tile < 512; tile += NBLK)
            gemm_tile(shpool, a.src_emb, a.eWih, a.eb, a.Xc,
                      a.x_seqs, c0 * B, tile & 15, tile >> 4);
        gbar(a.flags, a.rel, ep);
        for (int tl = 0; tl < CHUNK; ++tl) {
            int t = c0 + tl;
            if (bid < 128) {
                step_body<1, true, true, false>(shpool, bid,
                    Pl(0, t & 1, 0), Pl(0, t & 1, 1), Pl(0, t & 1, 2),
                    nullptr, nullptr, nullptr,
                    a.eP0, a.eP1, a.eP2,
                    a.Xc + (size_t)tl * B * G4,
                    a.hf32 + (size_t)(t & 1) * BH, a.hf32 + (size_t)((t + 1) & 1) * BH,
                    a.cbuf,
                    Pl(0, (t + 1) & 1, 0), Pl(0, (t + 1) & 1, 1), Pl(0, (t + 1) & 1, 2),
                    a.x_len, t, nullptr, 0);
            } else if (t >= 1) {
                int u = t - 1;
                step_body<2, false, true, false>(shpool, bid - 128,
                    Pl(1, u & 1, 0), Pl(1, u & 1, 1), Pl(1, u & 1, 2),
                    Pl(0, t & 1, 0), Pl(0, t & 1, 1), Pl(0, t & 1, 2),
                    a.e1P0, a.e1P1, a.e1P2,
                    a.ebint,
                    a.hf32 + (size_t)(2 + (u & 1)) * BH, a.hf32 + (size_t)(2 + ((u + 1) & 1)) * BH,
                    a.cbuf + BH,
                    Pl(1, (u + 1) & 1, 0), Pl(1, (u + 1) & 1, 1), Pl(1, (u + 1) & 1, 2),
                    a.x_len, u, nullptr, 0);
            }
            gbar(a.flags, a.rel, ep);
        }
    }
    if (bid < 128) {           // drain: L1 step 127
        int u = S - 1;
        step_body<2, false, true, false>(shpool, bid,
            Pl(1, u & 1, 0), Pl(1, u & 1, 1), Pl(1, u & 1, 2),
            Pl(0, (u + 1) & 1, 0), Pl(0, (u + 1) & 1, 1), Pl(0, (u + 1) & 1, 2),
            a.e1P0, a.e1P1, a.e1P2,
            a.ebint,
            a.hf32 + (size_t)(2 + (u & 1)) * BH, a.hf32 + (size_t)(2 + ((u + 1) & 1)) * BH,
            a.cbuf + BH,
            Pl(1, (u + 1) & 1, 0), Pl(1, (u + 1) & 1, 1), Pl(1, (u + 1) & 1, 2),
            a.x_len, u, nullptr, 0);
    }
    gbar(a.flags, a.rel, ep);

    // ---- genW -> bf16 (fresh region) + BOS x-splits ----
    {
        const int N8 = V * E / 8;
        for (int i = gtid; i < N8; i += GS) {
            float4 x = *(const float4*)(a.genW + (size_t)i * 8);
            float4 y = *(const float4*)(a.genW + (size_t)i * 8 + 4);
            __hip_bfloat16 tmp[8];
            tmp[0] = __float2bfloat16(x.x); tmp[1] = __float2bfloat16(x.y);
            tmp[2] = __float2bfloat16(x.z); tmp[3] = __float2bfloat16(x.w);
            tmp[4] = __float2bfloat16(y.x); tmp[5] = __float2bfloat16(y.y);
            tmp[6] = __float2bfloat16(y.z); tmp[7] = __float2bfloat16(y.w);
            st_coh_b128(a.Wbf + (size_t)i * 8, *(const short8v*)tmp);
        }
        for (int i = gtid; i < BH; i += GS) {
            int k = i & 511;
            float w = a.tgt_emb[512 + k];          // BOS token = 1
            __hip_bfloat16 s0, s1, s2; split3(w, s0, s1, s2);
            st_coh_b16(a.xP + i, s0);
            st_coh_b16(a.xP + BH + i, s1);
            st_coh_b16(a.xP + 2 * BH + i, s2);
        }
    }
    gbar(a.flags, a.rel, ep);

    // ---- decoder: 3 phases/step; reduce(t-1) overlaps L0(t) via x-ready flags ----
    for (int t = 0; t < TM1; ++t) {
        int si = t & 1, so = si ^ 1;
        // Phase A: L0(t) on 0..127 (x-half flag-gated) || reduce(t-1) on 128..191
        if (bid < 128)
            step_body<2, false, false, true>(shpool, bid,
                Pl(0, si, 0), Pl(0, si, 1), Pl(0, si, 2),
                a.xP, a.xP + BH, a.xP + 2 * BH,
                a.dP0, a.dP1, a.dP2, a.bint,
                nullptr, nullptr, a.cbuf,
                Pl(0, so, 0), Pl(0, so, 1), Pl(0, so, 2),
                nullptr, 0, a.xrdy, t);
        else if (bid < 192 && t >= 1)
            reduce_body(shpool, bid - 128, a.part, a.dech1, a.genW, a.genb, a.tgt_emb,
                        a.y_seqs, a.teacher, a.outp,
                        a.xP, a.xP + BH, a.xP + 2 * BH, t - 1, a.xrdy);
        gbar(a.flags, a.rel, ep);
        // Phase B: L1(t)
        if (bid < 128)
            step_body<2, false, false, false>(shpool, bid,
                Pl(1, si, 0), Pl(1, si, 1), Pl(1, si, 2),
                Pl(0, so, 0), Pl(0, so, 1), Pl(0, so, 2),
                a.dP0 + (size_t)G4 * 1024, a.dP1 + (size_t)G4 * 1024,
                a.dP2 + (size_t)G4 * 1024, a.bint + G4,
                nullptr, a.dech1, a.cbuf + BH,
                Pl(1, so, 0), Pl(1, so, 1), Pl(1, so, 2),
                nullptr, 0, nullptr, 0);
        gbar(a.flags, a.rel, ep);
        // Phase C: gen(t)
        if (bid < NTILES)
            gen_body(shpool, bid, Pl(1, so, 0), a.Wbf, a.genb, a.part);
        gbar(a.flags, a.rel, ep);
    }
    // final reduce for t = TM1-1 (no flag publication needed)
    if (bid >= 128 && bid < 192)
        reduce_body(shpool, bid - 128, a.part, a.dech1, a.genW, a.genb, a.tgt_emb,
                    a.y_seqs, a.teacher, a.outp,
                    a.xP, a.xP + BH, a.xP + 2 * BH, TM1 - 1, nullptr);
}

} // namespace

extern "C" void kernel_launch(void* const* d_in, const int* in_sizes, int n_in,
                              void* d_out, int out_size, void* d_ws, size_t ws_size,
                              hipStream_t stream)
{
    (void)in_sizes; (void)n_in; (void)out_size;
    const int*   x_seqs  = (const int*)  d_in[0];
    const int*   x_len   = (const int*)  d_in[1];
    const int*   y_seqs  = (const int*)  d_in[2];
    const int*   teacher = (const int*)  d_in[3];
    const float* src_emb = (const float*)d_in[4];
    const float* tgt_emb = (const float*)d_in[5];
    const float* eWih    = (const float*)d_in[6];
    const float* eWhh    = (const float*)d_in[7];
    const float* eb      = (const float*)d_in[8];
    const float* dWih    = (const float*)d_in[9];
    const float* dWhh    = (const float*)d_in[10];
    const float* db      = (const float*)d_in[11];
    const float* genW    = (const float*)d_in[12];
    const float* genb    = (const float*)d_in[13];

    float* w = (float*)d_ws;
    size_t off = 0;
    auto take = [&](size_t n) { float* p = w + off; off += n; return p; };
    auto takeb = [&](size_t n) { return (__hip_bfloat16*)take((n + 1) / 2); };

    unsigned* flags = (unsigned*)take(256 * 32);
    unsigned* rel   = (unsigned*)take(256 * 32);
    unsigned* xrdy  = (unsigned*)take(64 * 32);
    float* Xc = take((size_t)CHUNK * B * G4);                     // 16.78 MB
    __hip_bfloat16* eP0  = takeb((size_t)G4 * 512);
    __hip_bfloat16* eP1  = takeb((size_t)G4 * 512);
    __hip_bfloat16* eP2  = takeb((size_t)G4 * 512);
    __hip_bfloat16* e1P0 = takeb((size_t)G4 * 1024);
    __hip_bfloat16* e1P1 = takeb((size_t)G4 * 1024);
    __hip_bfloat16* e1P2 = takeb((size_t)G4 * 1024);
    float* ebint = take((size_t)G4);
    __hip_bfloat16* dP0 = takeb((size_t)2 * G4 * 1024);
    __hip_bfloat16* dP1 = takeb((size_t)2 * G4 * 1024);
    __hip_bfloat16* dP2 = takeb((size_t)2 * G4 * 1024);
    float* bint  = take(2 * (size_t)G4);
    float* hf32  = take(4 * (size_t)BH);
    float* cbuf  = take(2 * (size_t)BH);
    float* dech1 = take((size_t)BH);
    __hip_bfloat16* P  = takeb((size_t)12 * BH);
    __hip_bfloat16* xP = takeb((size_t)3 * BH);
    float* part_f = take((size_t)NTILES * B * 6);
    // FRESH Wbf region (32.8MB): never cached-accessed -> nt reads are safe
    __hip_bfloat16* Wbf = takeb((size_t)V * E);
    if (ws_size < off * sizeof(float)) return;    // fail visibly if ws too small

    dim3 tpb256(256);
    split_enc_k<<<dim3(G4), tpb256, 0, stream>>>(eWhh, eP0, eP1, eP2);
    split_dec_k<<<dim3(G4), tpb256, 0, stream>>>(
        eWih + (size_t)G4 * E, eWhh + (size_t)G4 * E, eb + G4, e1P0, e1P1, e1P2, ebint);
    split_dec_k<<<dim3(2 * G4), tpb256, 0, stream>>>(
        dWih, dWhh, db, dP0, dP1, dP2, bint);
    hipError_t _e = hipMemsetAsync(flags, 0, (2 * 256 + 64) * 32 * sizeof(unsigned), stream);
    (void)_e;

    Args a;
    a.x_seqs = x_seqs; a.x_len = x_len; a.y_seqs = y_seqs; a.teacher = teacher;
    a.src_emb = src_emb; a.tgt_emb = tgt_emb; a.eWih = eWih; a.eb = eb;
    a.genW = genW; a.genb = genb;
    a.Xc = Xc;
    a.eP0 = eP0; a.eP1 = eP1; a.eP2 = eP2;
    a.e1P0 = e1P0; a.e1P1 = e1P1; a.e1P2 = e1P2; a.ebint = ebint;
    a.dP0 = dP0; a.dP1 = dP1; a.dP2 = dP2; a.bint = bint;
    a.hf32 = hf32; a.cbuf = cbuf; a.dech1 = dech1;
    a.P = P; a.xP = xP;
    a.Wbf = Wbf;
    a.part = part_f;
    a.outp = (float*)d_out;
    a.flags = flags; a.rel = rel; a.xrdy = xrdy;

    persist_k<<<dim3(NBLK), tpb256, 0, stream>>>(a);
}